// Round 2
// baseline (463.528 us; speedup 1.0000x reference)
//
#include <hip/hip_runtime.h>

// SubgraphPooling: padded-table counting scatter + segmented reduction.
// out[s,:] = mean over edges e with sid[e]==s of feat[nid[e],:]
// N_NODES=100000, D=128, E=2000000, N_SEG=250000
//
// R6 changes vs R5 (429us):
//  - Eliminate scan_local/scan_blocks/reorder: hist scatters nid directly to
//    padded[s*32 + rank] (one 128B line per segment). 6 dispatches -> 3.
//    Atomic stream and scatter stream now overlap in one kernel instead of
//    running serially with a scan between them.
//  - Overflow (rank>=32, ~never for Poisson(8) data) goes to an exact
//    device-side overflow list drained by reduce -> correct for ANY data.
//  - Reduce reads padded row + cnt only (off/bsum gone).

constexpr int N_SEG   = 250000;
constexpr int SEG_CAP = 32;      // padded slots per segment = one 128B line
constexpr int OVF_CAP = 65536;

// ---- padded-path workspace layout ----
// [0, 1000000)            cnt   int[N_SEG]
// [1000000, 1000004)      ovf_cnt int
// [1MiB, 1MiB+512KB)      ovf   int2[OVF_CAP]   (sid, nid)
// [4MiB, 4MiB+32000000)   padded int[N_SEG*32]
#define PP_CNT(ws)     ((int*)((char*)(ws) + 0))
#define PP_OVFCNT(ws)  ((int*)((char*)(ws) + 1000000))
#define PP_OVF(ws)     ((int2*)((char*)(ws) + (1u<<20)))
#define PP_PAD(ws)     ((int*)((char*)(ws) + (4u<<20)))
constexpr size_t PP_WS_NEED = (size_t)(4u << 20) + (size_t)N_SEG * SEG_CAP * 4;

// ---- fallback (verified R5 rank path, needs >= 20 MiB) ----
constexpr int SCAN_CHUNK  = 1024;
constexpr int SCAN_BLOCKS = (N_SEG + SCAN_CHUNK - 1) / SCAN_CHUNK;  // 245
#define RP_CNT(ws)     ((int*)((char*)(ws) + 0))
#define RP_OFF(ws)     ((int*)((char*)(ws) + (1u<<20)))
#define RP_BSUM(ws)    ((int*)((char*)(ws) + (2u<<20)))
#define RP_RANK(ws)    ((int*)((char*)(ws) + (4u<<20)))
#define RP_SORTED(ws)  ((int*)((char*)(ws) + (12u<<20)))

typedef float nt4 __attribute__((ext_vector_type(4)));

// ---------------- padded path ----------------

// Fused histogram + direct padded scatter. rank comes straight from the
// atomicAdd return; no scan, no reorder pass.
__global__ __launch_bounds__(256) void sp_hist_scatter(
    const int* __restrict__ sid, const int* __restrict__ nid,
    int* __restrict__ cnt, int* __restrict__ padded,
    int* __restrict__ ovf_cnt, int2* __restrict__ ovf, int n)
{
    int i = blockIdx.x * blockDim.x + threadIdx.x;
    if (i >= n) return;
    int s = __builtin_nontemporal_load(&sid[i]);
    int v = __builtin_nontemporal_load(&nid[i]);
    int r = atomicAdd(&cnt[s], 1);
    if (r < SEG_CAP) {
        padded[(size_t)s * SEG_CAP + r] = v;   // one 128B line per segment
    } else {
        int o = atomicAdd(ovf_cnt, 1);
        if (o < OVF_CAP) ovf[o] = make_int2(s, v);
    }
}

// Reduce: one half-wave (32 lanes) per segment; lane = one float4 chunk.
// 8-deep clamped prefetch keeps 8 row loads in flight.
__global__ __launch_bounds__(256) void sp_reduce_pad(
    const float4* __restrict__ feat4,      // [N_NODES][32] float4
    const int* __restrict__ padded,
    const int* __restrict__ cnt,
    const int* __restrict__ ovf_cnt,
    const int2* __restrict__ ovf,
    float4* __restrict__ out4)             // [N_SEG][32] float4
{
    int seg  = blockIdx.x * 8 + (threadIdx.x >> 5);
    int lane = threadIdx.x & 31;
    if (seg >= N_SEG) return;

    int n = cnt[seg];
    int m = (n < SEG_CAP) ? n : SEG_CAP;
    int myid = (lane < m) ? padded[(size_t)seg * SEG_CAP + lane] : 0;

    float4 acc0 = make_float4(0.f, 0.f, 0.f, 0.f);
    float4 acc1 = make_float4(0.f, 0.f, 0.f, 0.f);

    if (m > 0) {
        int last = m - 1;
        for (int j0 = 0; j0 < m; j0 += 8) {
            int id[8];
#pragma unroll
            for (int k = 0; k < 8; ++k) {
                int jj = j0 + k;
                id[k] = __shfl(myid, (jj < last) ? jj : last, 32);
            }
            float4 b[8];
#pragma unroll
            for (int k = 0; k < 8; ++k)
                b[k] = feat4[(size_t)id[k] * 32 + lane];
#pragma unroll
            for (int k = 0; k < 8; ++k) {
                if (j0 + k < m) {
                    if (k & 1) {
                        acc1.x += b[k].x; acc1.y += b[k].y;
                        acc1.z += b[k].z; acc1.w += b[k].w;
                    } else {
                        acc0.x += b[k].x; acc0.y += b[k].y;
                        acc0.z += b[k].z; acc0.w += b[k].w;
                    }
                }
            }
        }
        // exact overflow drain (rank >= 32; effectively never for this data)
        if (n > SEG_CAP) {
            int on = *ovf_cnt;
            if (on > OVF_CAP) on = OVF_CAP;
            for (int k = 0; k < on; ++k) {
                int2 p = ovf[k];
                if (p.x == seg) {
                    float4 a = feat4[(size_t)p.y * 32 + lane];
                    acc0.x += a.x; acc0.y += a.y;
                    acc0.z += a.z; acc0.w += a.w;
                }
            }
        }
    }

    float inv = 1.0f / (float)((n > 0) ? n : 1);
    nt4 r;
    r.x = (acc0.x + acc1.x) * inv;
    r.y = (acc0.y + acc1.y) * inv;
    r.z = (acc0.z + acc1.z) * inv;
    r.w = (acc0.w + acc1.w) * inv;
    // NT store: don't let the 128MB output evict the feat table from L2.
    __builtin_nontemporal_store(
        r, reinterpret_cast<nt4*>(out4) + (size_t)seg * 32 + lane);
}

// ---------------- fallback path (verified R5) ----------------

__global__ __launch_bounds__(256) void sp_hist_rank(
    const int* __restrict__ sid, int* __restrict__ cnt,
    int* __restrict__ rank, int n)
{
    int i = blockIdx.x * blockDim.x + threadIdx.x;
    if (i >= n) return;
    int s = __builtin_nontemporal_load(&sid[i]);
    int r = atomicAdd(&cnt[s], 1);
    if (rank) __builtin_nontemporal_store(r, &rank[i]);
}

__global__ __launch_bounds__(256) void sp_scan_local(
    const int* __restrict__ cnt, int* __restrict__ off, int* __restrict__ bsum)
{
    __shared__ int sh[256];
    int tid  = threadIdx.x;
    int base = blockIdx.x * SCAN_CHUNK + tid * 4;
    int v0 = (base + 0 < N_SEG) ? cnt[base + 0] : 0;
    int v1 = (base + 1 < N_SEG) ? cnt[base + 1] : 0;
    int v2 = (base + 2 < N_SEG) ? cnt[base + 2] : 0;
    int v3 = (base + 3 < N_SEG) ? cnt[base + 3] : 0;
    sh[tid] = v0 + v1 + v2 + v3;
    __syncthreads();
    for (int o = 1; o < 256; o <<= 1) {
        int t = (tid >= o) ? sh[tid - o] : 0;
        __syncthreads();
        sh[tid] += t;
        __syncthreads();
    }
    int excl = (tid > 0) ? sh[tid - 1] : 0;
    if (base + 0 < N_SEG) off[base + 0] = excl;
    if (base + 1 < N_SEG) off[base + 1] = excl + v0;
    if (base + 2 < N_SEG) off[base + 2] = excl + v0 + v1;
    if (base + 3 < N_SEG) off[base + 3] = excl + v0 + v1 + v2;
    if (tid == 255) bsum[blockIdx.x] = sh[255];
}

__global__ __launch_bounds__(256) void sp_scan_blocks(int* __restrict__ bsum)
{
    __shared__ int sh[256];
    int tid = threadIdx.x;
    int v = (tid < SCAN_BLOCKS) ? bsum[tid] : 0;
    sh[tid] = v;
    __syncthreads();
    for (int o = 1; o < 256; o <<= 1) {
        int t = (tid >= o) ? sh[tid - o] : 0;
        __syncthreads();
        sh[tid] += t;
        __syncthreads();
    }
    if (tid < SCAN_BLOCKS) bsum[tid] = sh[tid] - v;
}

__global__ __launch_bounds__(256) void sp_reorder_rank(
    const int* __restrict__ nid, const int* __restrict__ sid,
    const int* __restrict__ off, const int* __restrict__ bsum,
    const int* __restrict__ rank, int* __restrict__ sorted_nid, int n)
{
    int i = blockIdx.x * blockDim.x + threadIdx.x;
    if (i >= n) return;
    int s = __builtin_nontemporal_load(&sid[i]);
    int r = __builtin_nontemporal_load(&rank[i]);
    int v = __builtin_nontemporal_load(&nid[i]);
    sorted_nid[off[s] + bsum[s >> 10] + r] = v;
}

__global__ __launch_bounds__(256) void sp_reduce(
    const float4* __restrict__ feat4,
    const int* __restrict__ sorted_nid,
    const int* __restrict__ off,
    const int* __restrict__ bsum,
    const int* __restrict__ cnt,
    float4* __restrict__ out4)
{
    int seg  = blockIdx.x * 8 + (threadIdx.x >> 5);
    int lane = threadIdx.x & 31;
    if (seg >= N_SEG) return;

    int n   = cnt[seg];
    int beg = off[seg] + bsum[seg >> 10];
    int m   = (n < 32) ? n : 32;
    int myid = (lane < m) ? sorted_nid[beg + lane] : 0;

    float4 acc0 = make_float4(0.f, 0.f, 0.f, 0.f);
    float4 acc1 = make_float4(0.f, 0.f, 0.f, 0.f);

    if (m > 0) {
        int last = m - 1;
        for (int j0 = 0; j0 < m; j0 += 8) {
            int id[8];
#pragma unroll
            for (int k = 0; k < 8; ++k) {
                int jj = j0 + k;
                id[k] = __shfl(myid, (jj < last) ? jj : last, 32);
            }
            float4 b[8];
#pragma unroll
            for (int k = 0; k < 8; ++k)
                b[k] = feat4[(size_t)id[k] * 32 + lane];
#pragma unroll
            for (int k = 0; k < 8; ++k) {
                if (j0 + k < m) {
                    if (k & 1) {
                        acc1.x += b[k].x; acc1.y += b[k].y;
                        acc1.z += b[k].z; acc1.w += b[k].w;
                    } else {
                        acc0.x += b[k].x; acc0.y += b[k].y;
                        acc0.z += b[k].z; acc0.w += b[k].w;
                    }
                }
            }
        }
        for (int k = 32; k < n; ++k) {
            int nk = sorted_nid[beg + k];
            float4 a = feat4[(size_t)nk * 32 + lane];
            acc0.x += a.x; acc0.y += a.y; acc0.z += a.z; acc0.w += a.w;
        }
    }

    float inv = 1.0f / (float)((n > 0) ? n : 1);
    nt4 r;
    r.x = (acc0.x + acc1.x) * inv;
    r.y = (acc0.y + acc1.y) * inv;
    r.z = (acc0.z + acc1.z) * inv;
    r.w = (acc0.w + acc1.w) * inv;
    __builtin_nontemporal_store(
        r, reinterpret_cast<nt4*>(out4) + (size_t)seg * 32 + lane);
}

// ---------------- launch ----------------

extern "C" void kernel_launch(void* const* d_in, const int* in_sizes, int n_in,
                              void* d_out, int out_size, void* d_ws, size_t ws_size,
                              hipStream_t stream) {
    const float* feat = (const float*)d_in[0];
    const int*   nid  = (const int*)d_in[1];
    const int*   sid  = (const int*)d_in[2];
    const int n_edges = in_sizes[1];

    int eb = (n_edges + 255) / 256;
    int rb = (N_SEG + 7) / 8;

    if (ws_size >= PP_WS_NEED) {
        // padded path: 3 dispatches total
        int* cnt     = PP_CNT(d_ws);
        int* ovf_cnt = PP_OVFCNT(d_ws);
        int2* ovf    = PP_OVF(d_ws);
        int* padded  = PP_PAD(d_ws);

        // zero cnt (1,000,000 B) + ovf_cnt (4 B) in one memset
        hipMemsetAsync(d_ws, 0, 1000004, stream);
        sp_hist_scatter<<<eb, 256, 0, stream>>>(sid, nid, cnt, padded,
                                                ovf_cnt, ovf, n_edges);
        sp_reduce_pad<<<rb, 256, 0, stream>>>((const float4*)feat, padded, cnt,
                                              ovf_cnt, ovf, (float4*)d_out);
    } else {
        // fallback: verified R5 rank path
        int* cnt    = RP_CNT(d_ws);
        int* off    = RP_OFF(d_ws);
        int* bsum   = RP_BSUM(d_ws);
        int* rank   = RP_RANK(d_ws);
        int* sorted = RP_SORTED(d_ws);

        hipMemsetAsync(d_ws, 0, (size_t)(1u << 20), stream);
        sp_hist_rank<<<eb, 256, 0, stream>>>(sid, cnt, rank, n_edges);
        sp_scan_local<<<SCAN_BLOCKS, 256, 0, stream>>>(cnt, off, bsum);
        sp_scan_blocks<<<1, 256, 0, stream>>>(bsum);
        sp_reorder_rank<<<eb, 256, 0, stream>>>(nid, sid, off, bsum, rank,
                                                sorted, n_edges);
        sp_reduce<<<rb, 256, 0, stream>>>((const float4*)feat, sorted, off,
                                          bsum, cnt, (float4*)d_out);
    }
}

// Round 4
// 380.735 us; speedup vs baseline: 1.2175x; 1.2175x over previous
//
#include <hip/hip_runtime.h>
#include <hip/hip_fp16.h>

// SubgraphPooling via counting-sort (rank path) + fp16-table segmented reduce.
// out[s,:] = mean over edges e with sid[e]==s of feat[nid[e],:]
// N_NODES=100000, D=128, E=2000000, N_SEG=250000
//
// R8 = R7 with the compile fix: __builtin_nontemporal_load needs a native
// vector type, not HIP_vector_type -> load via ext_vector_type(4) alias.
//
// R7 rationale vs R5/429us (R6 padded-table scatter REGRESSED to 463us:
// 122MB partial-line writebacks for 8MB payload + atomic->scatter chaining;
// reverted to the verified R5 rank pipeline):
//  - feat is converted once per launch to an fp16 table in workspace (~12us
//    streaming pass). The reduce's 471MB fetch is ~8 XCDs x 51MB table
//    (structural per-XCD refetch of a random gather) -> halving the table
//    halves the fetch. Accumulation stays fp32; quantization error ~2e-3
//    vs 7.8e-3 tolerance.
//  - fp32 path kept verbatim as fallback if workspace is too small.

constexpr int N_NODES = 100000;
constexpr int D_FEAT  = 128;
constexpr int N_SEG   = 250000;
constexpr int SCAN_CHUNK  = 1024;                                   // 256 thr x 4
constexpr int SCAN_BLOCKS = (N_SEG + SCAN_CHUNK - 1) / SCAN_CHUNK;  // 245

// ---- workspace layout ----
// [0,1MB) cnt | [1MB,2MB) off | [2MB,2MB+1KB) bsum | [4MB,12MB) rank
// [12MB,20MB) sorted | [20MB, 20MB+25.6MB) feat16
#define RP_CNT(ws)     ((int*)((char*)(ws) + 0))
#define RP_OFF(ws)     ((int*)((char*)(ws) + (1u<<20)))
#define RP_BSUM(ws)    ((int*)((char*)(ws) + (2u<<20)))
#define RP_RANK(ws)    ((int*)((char*)(ws) + (4u<<20)))
#define RP_SORTED(ws)  ((int*)((char*)(ws) + (12u<<20)))
#define RP_FEAT16(ws)  ((char*)(ws) + (20u<<20))
constexpr size_t FP16_BYTES = (size_t)N_NODES * D_FEAT * 2;          // 25.6 MB
constexpr size_t WS_NEED_H  = (size_t)(20u << 20) + FP16_BYTES;      // ~46.6 MB

typedef float nt4 __attribute__((ext_vector_type(4)));
typedef unsigned int ntu4 __attribute__((ext_vector_type(4)));

// ---------------- shared sort-side kernels (verified R5) ----------------

__global__ __launch_bounds__(256) void sp_hist_rank(
    const int* __restrict__ sid, int* __restrict__ cnt,
    int* __restrict__ rank, int n)
{
    int i = blockIdx.x * blockDim.x + threadIdx.x;
    if (i >= n) return;
    int s = __builtin_nontemporal_load(&sid[i]);
    int r = atomicAdd(&cnt[s], 1);
    __builtin_nontemporal_store(r, &rank[i]);
}

__global__ __launch_bounds__(256) void sp_scan_local(
    const int* __restrict__ cnt, int* __restrict__ off, int* __restrict__ bsum)
{
    __shared__ int sh[256];
    int tid  = threadIdx.x;
    int base = blockIdx.x * SCAN_CHUNK + tid * 4;
    int v0 = (base + 0 < N_SEG) ? cnt[base + 0] : 0;
    int v1 = (base + 1 < N_SEG) ? cnt[base + 1] : 0;
    int v2 = (base + 2 < N_SEG) ? cnt[base + 2] : 0;
    int v3 = (base + 3 < N_SEG) ? cnt[base + 3] : 0;
    sh[tid] = v0 + v1 + v2 + v3;
    __syncthreads();
    for (int o = 1; o < 256; o <<= 1) {
        int t = (tid >= o) ? sh[tid - o] : 0;
        __syncthreads();
        sh[tid] += t;
        __syncthreads();
    }
    int excl = (tid > 0) ? sh[tid - 1] : 0;
    if (base + 0 < N_SEG) off[base + 0] = excl;
    if (base + 1 < N_SEG) off[base + 1] = excl + v0;
    if (base + 2 < N_SEG) off[base + 2] = excl + v0 + v1;
    if (base + 3 < N_SEG) off[base + 3] = excl + v0 + v1 + v2;
    if (tid == 255) bsum[blockIdx.x] = sh[255];
}

__global__ __launch_bounds__(256) void sp_scan_blocks(int* __restrict__ bsum)
{
    __shared__ int sh[256];
    int tid = threadIdx.x;
    int v = (tid < SCAN_BLOCKS) ? bsum[tid] : 0;
    sh[tid] = v;
    __syncthreads();
    for (int o = 1; o < 256; o <<= 1) {
        int t = (tid >= o) ? sh[tid - o] : 0;
        __syncthreads();
        sh[tid] += t;
        __syncthreads();
    }
    if (tid < SCAN_BLOCKS) bsum[tid] = sh[tid] - v;   // inclusive -> exclusive
}

__global__ __launch_bounds__(256) void sp_reorder_rank(
    const int* __restrict__ nid, const int* __restrict__ sid,
    const int* __restrict__ off, const int* __restrict__ bsum,
    const int* __restrict__ rank, int* __restrict__ sorted_nid, int n)
{
    int i = blockIdx.x * blockDim.x + threadIdx.x;
    if (i >= n) return;
    int s = __builtin_nontemporal_load(&sid[i]);
    int r = __builtin_nontemporal_load(&rank[i]);
    int v = __builtin_nontemporal_load(&nid[i]);
    sorted_nid[off[s] + bsum[s >> 10] + r] = v;
}

// ---------------- fp16 path ----------------

// feat fp32 -> fp16 table, 8 floats per thread (16B read x2, 16B write).
__global__ __launch_bounds__(256) void sp_cvt(
    const float* __restrict__ in, unsigned int* __restrict__ out, int n8)
{
    int i = blockIdx.x * blockDim.x + threadIdx.x;
    if (i >= n8) return;
    const nt4* in4 = (const nt4*)in;
    nt4 v0 = __builtin_nontemporal_load(&in4[2 * i + 0]);
    nt4 v1 = __builtin_nontemporal_load(&in4[2 * i + 1]);
    __half2 h0 = __floats2half2_rn(v0.x, v0.y);
    __half2 h1 = __floats2half2_rn(v0.z, v0.w);
    __half2 h2 = __floats2half2_rn(v1.x, v1.y);
    __half2 h3 = __floats2half2_rn(v1.z, v1.w);
    ntu4 o;
    o.x = *(const unsigned int*)&h0;
    o.y = *(const unsigned int*)&h1;
    o.z = *(const unsigned int*)&h2;
    o.w = *(const unsigned int*)&h3;
    __builtin_nontemporal_store(o, (ntu4*)out + i);
}

__device__ __forceinline__ float2 h2f(unsigned short lo, unsigned short hi)
{
    __half2 h = __halves2half2(__ushort_as_half(lo), __ushort_as_half(hi));
    return __half22float2(h);
}

__device__ __forceinline__ void acc_h(float4& acc, const ushort4& b)
{
    float2 f01 = h2f(b.x, b.y);
    float2 f23 = h2f(b.z, b.w);
    acc.x += f01.x; acc.y += f01.y; acc.z += f23.x; acc.w += f23.y;
}

// Reduce from the fp16 table: one half-wave per segment, lane = 4 dims (8B).
__global__ __launch_bounds__(256) void sp_reduce_h(
    const ushort4* __restrict__ feat16,    // [N_NODES][32] ushort4
    const int* __restrict__ sorted_nid,
    const int* __restrict__ off,
    const int* __restrict__ bsum,
    const int* __restrict__ cnt,
    float4* __restrict__ out4)             // [N_SEG][32] float4
{
    int seg  = blockIdx.x * 8 + (threadIdx.x >> 5);
    int lane = threadIdx.x & 31;
    if (seg >= N_SEG) return;

    int n   = cnt[seg];
    int beg = off[seg] + bsum[seg >> 10];
    int m   = (n < 32) ? n : 32;
    int myid = (lane < m) ? sorted_nid[beg + lane] : 0;

    float4 acc0 = make_float4(0.f, 0.f, 0.f, 0.f);
    float4 acc1 = make_float4(0.f, 0.f, 0.f, 0.f);

    if (m > 0) {
        int last = m - 1;
        for (int j0 = 0; j0 < m; j0 += 8) {
            int id[8];
#pragma unroll
            for (int k = 0; k < 8; ++k) {
                int jj = j0 + k;
                id[k] = __shfl(myid, (jj < last) ? jj : last, 32);
            }
            ushort4 b[8];
#pragma unroll
            for (int k = 0; k < 8; ++k)
                b[k] = feat16[(size_t)id[k] * 32 + lane];
#pragma unroll
            for (int k = 0; k < 8; ++k) {
                if (j0 + k < m) {
                    if (k & 1) acc_h(acc1, b[k]);
                    else       acc_h(acc0, b[k]);
                }
            }
        }
        for (int k = 32; k < n; ++k) {     // pathological n>32 fallback
            int nk = sorted_nid[beg + k];
            acc_h(acc0, feat16[(size_t)nk * 32 + lane]);
        }
    }

    float inv = 1.0f / (float)((n > 0) ? n : 1);
    nt4 r;
    r.x = (acc0.x + acc1.x) * inv;
    r.y = (acc0.y + acc1.y) * inv;
    r.z = (acc0.z + acc1.z) * inv;
    r.w = (acc0.w + acc1.w) * inv;
    __builtin_nontemporal_store(
        r, reinterpret_cast<nt4*>(out4) + (size_t)seg * 32 + lane);
}

// ---------------- fp32 fallback reduce (verified R5) ----------------

__global__ __launch_bounds__(256) void sp_reduce(
    const float4* __restrict__ feat4,
    const int* __restrict__ sorted_nid,
    const int* __restrict__ off,
    const int* __restrict__ bsum,
    const int* __restrict__ cnt,
    float4* __restrict__ out4)
{
    int seg  = blockIdx.x * 8 + (threadIdx.x >> 5);
    int lane = threadIdx.x & 31;
    if (seg >= N_SEG) return;

    int n   = cnt[seg];
    int beg = off[seg] + bsum[seg >> 10];
    int m   = (n < 32) ? n : 32;
    int myid = (lane < m) ? sorted_nid[beg + lane] : 0;

    float4 acc0 = make_float4(0.f, 0.f, 0.f, 0.f);
    float4 acc1 = make_float4(0.f, 0.f, 0.f, 0.f);

    if (m > 0) {
        int last = m - 1;
        for (int j0 = 0; j0 < m; j0 += 8) {
            int id[8];
#pragma unroll
            for (int k = 0; k < 8; ++k) {
                int jj = j0 + k;
                id[k] = __shfl(myid, (jj < last) ? jj : last, 32);
            }
            float4 b[8];
#pragma unroll
            for (int k = 0; k < 8; ++k)
                b[k] = feat4[(size_t)id[k] * 32 + lane];
#pragma unroll
            for (int k = 0; k < 8; ++k) {
                if (j0 + k < m) {
                    if (k & 1) {
                        acc1.x += b[k].x; acc1.y += b[k].y;
                        acc1.z += b[k].z; acc1.w += b[k].w;
                    } else {
                        acc0.x += b[k].x; acc0.y += b[k].y;
                        acc0.z += b[k].z; acc0.w += b[k].w;
                    }
                }
            }
        }
        for (int k = 32; k < n; ++k) {
            int nk = sorted_nid[beg + k];
            float4 a = feat4[(size_t)nk * 32 + lane];
            acc0.x += a.x; acc0.y += a.y; acc0.z += a.z; acc0.w += a.w;
        }
    }

    float inv = 1.0f / (float)((n > 0) ? n : 1);
    nt4 r;
    r.x = (acc0.x + acc1.x) * inv;
    r.y = (acc0.y + acc1.y) * inv;
    r.z = (acc0.z + acc1.z) * inv;
    r.w = (acc0.w + acc1.w) * inv;
    __builtin_nontemporal_store(
        r, reinterpret_cast<nt4*>(out4) + (size_t)seg * 32 + lane);
}

// ---------------- launch ----------------

extern "C" void kernel_launch(void* const* d_in, const int* in_sizes, int n_in,
                              void* d_out, int out_size, void* d_ws, size_t ws_size,
                              hipStream_t stream) {
    const float* feat = (const float*)d_in[0];
    const int*   nid  = (const int*)d_in[1];
    const int*   sid  = (const int*)d_in[2];
    const int n_edges = in_sizes[1];

    int eb = (n_edges + 255) / 256;
    int rb = (N_SEG + 7) / 8;

    int* cnt    = RP_CNT(d_ws);
    int* off    = RP_OFF(d_ws);
    int* bsum   = RP_BSUM(d_ws);
    int* rank   = RP_RANK(d_ws);
    int* sorted = RP_SORTED(d_ws);

    hipMemsetAsync(d_ws, 0, (size_t)(1u << 20), stream);

    if (ws_size >= WS_NEED_H) {
        // fp16-table path
        unsigned int* feat16 = (unsigned int*)RP_FEAT16(d_ws);
        int n8 = N_NODES * D_FEAT / 8;     // 1.6M elements of 8 floats
        sp_cvt<<<(n8 + 255) / 256, 256, 0, stream>>>(feat, feat16, n8);
        sp_hist_rank<<<eb, 256, 0, stream>>>(sid, cnt, rank, n_edges);
        sp_scan_local<<<SCAN_BLOCKS, 256, 0, stream>>>(cnt, off, bsum);
        sp_scan_blocks<<<1, 256, 0, stream>>>(bsum);
        sp_reorder_rank<<<eb, 256, 0, stream>>>(nid, sid, off, bsum, rank,
                                                sorted, n_edges);
        sp_reduce_h<<<rb, 256, 0, stream>>>((const ushort4*)feat16, sorted,
                                            off, bsum, cnt, (float4*)d_out);
    } else {
        // verified fp32 path
        sp_hist_rank<<<eb, 256, 0, stream>>>(sid, cnt, rank, n_edges);
        sp_scan_local<<<SCAN_BLOCKS, 256, 0, stream>>>(cnt, off, bsum);
        sp_scan_blocks<<<1, 256, 0, stream>>>(bsum);
        sp_reorder_rank<<<eb, 256, 0, stream>>>(nid, sid, off, bsum, rank,
                                                sorted, n_edges);
        sp_reduce<<<rb, 256, 0, stream>>>((const float4*)feat, sorted, off,
                                          bsum, cnt, (float4*)d_out);
    }
}

// Round 5
// 374.268 us; speedup vs baseline: 1.2385x; 1.0173x over previous
//
#include <hip/hip_runtime.h>
#include <hip/hip_fp16.h>

// SubgraphPooling via counting-sort (rank path) + fp16-table segmented reduce.
// out[s,:] = mean over edges e with sid[e]==s of feat[nid[e],:]
// N_NODES=100000, D=128, E=2000000, N_SEG=250000
//
// R9 changes vs R8 (381us):
//  - hist/reorder were latency-bound at 1 random vmem op per thread:
//    ~25 waves/CU x 1 outstanding / ~900cy = 17 G transactions/s == measured.
//    Now 8 edges/thread: 8 independent atomics (hist) / 8 independent
//    scatter stores (reorder) in flight per thread -> 8x outstanding ops.
//  - reduce_h (89us) is at its structural floor (223MB = 8 XCDs x 25.6MB
//    fp16 table, per-XCD refetch of a random gather) - unchanged.

constexpr int N_NODES = 100000;
constexpr int D_FEAT  = 128;
constexpr int N_SEG   = 250000;
constexpr int SCAN_CHUNK  = 1024;                                   // 256 thr x 4
constexpr int SCAN_BLOCKS = (N_SEG + SCAN_CHUNK - 1) / SCAN_CHUNK;  // 245

// ---- workspace layout ----
// [0,1MB) cnt | [1MB,2MB) off | [2MB,2MB+1KB) bsum | [4MB,12MB) rank
// [12MB,20MB) sorted | [20MB, 20MB+25.6MB) feat16
#define RP_CNT(ws)     ((int*)((char*)(ws) + 0))
#define RP_OFF(ws)     ((int*)((char*)(ws) + (1u<<20)))
#define RP_BSUM(ws)    ((int*)((char*)(ws) + (2u<<20)))
#define RP_RANK(ws)    ((int*)((char*)(ws) + (4u<<20)))
#define RP_SORTED(ws)  ((int*)((char*)(ws) + (12u<<20)))
#define RP_FEAT16(ws)  ((char*)(ws) + (20u<<20))
constexpr size_t FP16_BYTES = (size_t)N_NODES * D_FEAT * 2;          // 25.6 MB
constexpr size_t WS_NEED_H  = (size_t)(20u << 20) + FP16_BYTES;      // ~46.6 MB

typedef float nt4 __attribute__((ext_vector_type(4)));
typedef unsigned int ntu4 __attribute__((ext_vector_type(4)));
typedef int nti4 __attribute__((ext_vector_type(4)));

// ---------------- sort side: 8 edges per thread ----------------

__global__ __launch_bounds__(256) void sp_hist_rank8(
    const int* __restrict__ sid, int* __restrict__ cnt,
    int* __restrict__ rank, int n)
{
    int i0 = (blockIdx.x * blockDim.x + threadIdx.x) * 8;
    if (i0 + 8 <= n) {
        nti4 a = __builtin_nontemporal_load((const nti4*)(sid + i0));
        nti4 b = __builtin_nontemporal_load((const nti4*)(sid + i0 + 4));
        // 8 independent atomics issued back-to-back -> 8 outstanding.
        int r0 = atomicAdd(&cnt[a.x], 1);
        int r1 = atomicAdd(&cnt[a.y], 1);
        int r2 = atomicAdd(&cnt[a.z], 1);
        int r3 = atomicAdd(&cnt[a.w], 1);
        int r4 = atomicAdd(&cnt[b.x], 1);
        int r5 = atomicAdd(&cnt[b.y], 1);
        int r6 = atomicAdd(&cnt[b.z], 1);
        int r7 = atomicAdd(&cnt[b.w], 1);
        nti4 ra; ra.x = r0; ra.y = r1; ra.z = r2; ra.w = r3;
        nti4 rb; rb.x = r4; rb.y = r5; rb.z = r6; rb.w = r7;
        __builtin_nontemporal_store(ra, (nti4*)(rank + i0));
        __builtin_nontemporal_store(rb, (nti4*)(rank + i0 + 4));
    } else {
        for (int k = 0; k < 8; ++k) {
            int i = i0 + k;
            if (i < n) rank[i] = atomicAdd(&cnt[sid[i]], 1);
        }
    }
}

__global__ __launch_bounds__(256) void sp_reorder_rank8(
    const int* __restrict__ nid, const int* __restrict__ sid,
    const int* __restrict__ off, const int* __restrict__ bsum,
    const int* __restrict__ rank, int* __restrict__ sorted_nid, int n)
{
    int i0 = (blockIdx.x * blockDim.x + threadIdx.x) * 8;
    if (i0 + 8 <= n) {
        nti4 sa = __builtin_nontemporal_load((const nti4*)(sid + i0));
        nti4 sb = __builtin_nontemporal_load((const nti4*)(sid + i0 + 4));
        nti4 ra = __builtin_nontemporal_load((const nti4*)(rank + i0));
        nti4 rb = __builtin_nontemporal_load((const nti4*)(rank + i0 + 4));
        nti4 va = __builtin_nontemporal_load((const nti4*)(nid + i0));
        nti4 vb = __builtin_nontemporal_load((const nti4*)(nid + i0 + 4));
        int s0 = sa.x, s1 = sa.y, s2 = sa.z, s3 = sa.w;
        int s4 = sb.x, s5 = sb.y, s6 = sb.z, s7 = sb.w;
        // independent random reads of off/bsum overlap; 8 independent
        // scatter stores are fire-and-forget.
        int p0 = off[s0] + bsum[s0 >> 10] + ra.x;
        int p1 = off[s1] + bsum[s1 >> 10] + ra.y;
        int p2 = off[s2] + bsum[s2 >> 10] + ra.z;
        int p3 = off[s3] + bsum[s3 >> 10] + ra.w;
        int p4 = off[s4] + bsum[s4 >> 10] + rb.x;
        int p5 = off[s5] + bsum[s5 >> 10] + rb.y;
        int p6 = off[s6] + bsum[s6 >> 10] + rb.z;
        int p7 = off[s7] + bsum[s7 >> 10] + rb.w;
        sorted_nid[p0] = va.x;
        sorted_nid[p1] = va.y;
        sorted_nid[p2] = va.z;
        sorted_nid[p3] = va.w;
        sorted_nid[p4] = vb.x;
        sorted_nid[p5] = vb.y;
        sorted_nid[p6] = vb.z;
        sorted_nid[p7] = vb.w;
    } else {
        for (int k = 0; k < 8; ++k) {
            int i = i0 + k;
            if (i < n) {
                int s = sid[i];
                sorted_nid[off[s] + bsum[s >> 10] + rank[i]] = nid[i];
            }
        }
    }
}

// ---------------- scans (verified) ----------------

__global__ __launch_bounds__(256) void sp_scan_local(
    const int* __restrict__ cnt, int* __restrict__ off, int* __restrict__ bsum)
{
    __shared__ int sh[256];
    int tid  = threadIdx.x;
    int base = blockIdx.x * SCAN_CHUNK + tid * 4;
    int v0 = (base + 0 < N_SEG) ? cnt[base + 0] : 0;
    int v1 = (base + 1 < N_SEG) ? cnt[base + 1] : 0;
    int v2 = (base + 2 < N_SEG) ? cnt[base + 2] : 0;
    int v3 = (base + 3 < N_SEG) ? cnt[base + 3] : 0;
    sh[tid] = v0 + v1 + v2 + v3;
    __syncthreads();
    for (int o = 1; o < 256; o <<= 1) {
        int t = (tid >= o) ? sh[tid - o] : 0;
        __syncthreads();
        sh[tid] += t;
        __syncthreads();
    }
    int excl = (tid > 0) ? sh[tid - 1] : 0;
    if (base + 0 < N_SEG) off[base + 0] = excl;
    if (base + 1 < N_SEG) off[base + 1] = excl + v0;
    if (base + 2 < N_SEG) off[base + 2] = excl + v0 + v1;
    if (base + 3 < N_SEG) off[base + 3] = excl + v0 + v1 + v2;
    if (tid == 255) bsum[blockIdx.x] = sh[255];
}

__global__ __launch_bounds__(256) void sp_scan_blocks(int* __restrict__ bsum)
{
    __shared__ int sh[256];
    int tid = threadIdx.x;
    int v = (tid < SCAN_BLOCKS) ? bsum[tid] : 0;
    sh[tid] = v;
    __syncthreads();
    for (int o = 1; o < 256; o <<= 1) {
        int t = (tid >= o) ? sh[tid - o] : 0;
        __syncthreads();
        sh[tid] += t;
        __syncthreads();
    }
    if (tid < SCAN_BLOCKS) bsum[tid] = sh[tid] - v;   // inclusive -> exclusive
}

// ---------------- fp16 path ----------------

__global__ __launch_bounds__(256) void sp_cvt(
    const float* __restrict__ in, unsigned int* __restrict__ out, int n8)
{
    int i = blockIdx.x * blockDim.x + threadIdx.x;
    if (i >= n8) return;
    const nt4* in4 = (const nt4*)in;
    nt4 v0 = __builtin_nontemporal_load(&in4[2 * i + 0]);
    nt4 v1 = __builtin_nontemporal_load(&in4[2 * i + 1]);
    __half2 h0 = __floats2half2_rn(v0.x, v0.y);
    __half2 h1 = __floats2half2_rn(v0.z, v0.w);
    __half2 h2 = __floats2half2_rn(v1.x, v1.y);
    __half2 h3 = __floats2half2_rn(v1.z, v1.w);
    ntu4 o;
    o.x = *(const unsigned int*)&h0;
    o.y = *(const unsigned int*)&h1;
    o.z = *(const unsigned int*)&h2;
    o.w = *(const unsigned int*)&h3;
    __builtin_nontemporal_store(o, (ntu4*)out + i);
}

__device__ __forceinline__ float2 h2f(unsigned short lo, unsigned short hi)
{
    __half2 h = __halves2half2(__ushort_as_half(lo), __ushort_as_half(hi));
    return __half22float2(h);
}

__device__ __forceinline__ void acc_h(float4& acc, const ushort4& b)
{
    float2 f01 = h2f(b.x, b.y);
    float2 f23 = h2f(b.z, b.w);
    acc.x += f01.x; acc.y += f01.y; acc.z += f23.x; acc.w += f23.y;
}

// Reduce from the fp16 table: one half-wave per segment, lane = 4 dims (8B).
__global__ __launch_bounds__(256) void sp_reduce_h(
    const ushort4* __restrict__ feat16,    // [N_NODES][32] ushort4
    const int* __restrict__ sorted_nid,
    const int* __restrict__ off,
    const int* __restrict__ bsum,
    const int* __restrict__ cnt,
    float4* __restrict__ out4)             // [N_SEG][32] float4
{
    int seg  = blockIdx.x * 8 + (threadIdx.x >> 5);
    int lane = threadIdx.x & 31;
    if (seg >= N_SEG) return;

    int n   = cnt[seg];
    int beg = off[seg] + bsum[seg >> 10];
    int m   = (n < 32) ? n : 32;
    int myid = (lane < m) ? sorted_nid[beg + lane] : 0;

    float4 acc0 = make_float4(0.f, 0.f, 0.f, 0.f);
    float4 acc1 = make_float4(0.f, 0.f, 0.f, 0.f);

    if (m > 0) {
        int last = m - 1;
        for (int j0 = 0; j0 < m; j0 += 8) {
            int id[8];
#pragma unroll
            for (int k = 0; k < 8; ++k) {
                int jj = j0 + k;
                id[k] = __shfl(myid, (jj < last) ? jj : last, 32);
            }
            ushort4 b[8];
#pragma unroll
            for (int k = 0; k < 8; ++k)
                b[k] = feat16[(size_t)id[k] * 32 + lane];
#pragma unroll
            for (int k = 0; k < 8; ++k) {
                if (j0 + k < m) {
                    if (k & 1) acc_h(acc1, b[k]);
                    else       acc_h(acc0, b[k]);
                }
            }
        }
        for (int k = 32; k < n; ++k) {     // pathological n>32 fallback
            int nk = sorted_nid[beg + k];
            acc_h(acc0, feat16[(size_t)nk * 32 + lane]);
        }
    }

    float inv = 1.0f / (float)((n > 0) ? n : 1);
    nt4 r;
    r.x = (acc0.x + acc1.x) * inv;
    r.y = (acc0.y + acc1.y) * inv;
    r.z = (acc0.z + acc1.z) * inv;
    r.w = (acc0.w + acc1.w) * inv;
    __builtin_nontemporal_store(
        r, reinterpret_cast<nt4*>(out4) + (size_t)seg * 32 + lane);
}

// ---------------- fp32 fallback reduce (verified R5) ----------------

__global__ __launch_bounds__(256) void sp_reduce(
    const float4* __restrict__ feat4,
    const int* __restrict__ sorted_nid,
    const int* __restrict__ off,
    const int* __restrict__ bsum,
    const int* __restrict__ cnt,
    float4* __restrict__ out4)
{
    int seg  = blockIdx.x * 8 + (threadIdx.x >> 5);
    int lane = threadIdx.x & 31;
    if (seg >= N_SEG) return;

    int n   = cnt[seg];
    int beg = off[seg] + bsum[seg >> 10];
    int m   = (n < 32) ? n : 32;
    int myid = (lane < m) ? sorted_nid[beg + lane] : 0;

    float4 acc0 = make_float4(0.f, 0.f, 0.f, 0.f);
    float4 acc1 = make_float4(0.f, 0.f, 0.f, 0.f);

    if (m > 0) {
        int last = m - 1;
        for (int j0 = 0; j0 < m; j0 += 8) {
            int id[8];
#pragma unroll
            for (int k = 0; k < 8; ++k) {
                int jj = j0 + k;
                id[k] = __shfl(myid, (jj < last) ? jj : last, 32);
            }
            float4 b[8];
#pragma unroll
            for (int k = 0; k < 8; ++k)
                b[k] = feat4[(size_t)id[k] * 32 + lane];
#pragma unroll
            for (int k = 0; k < 8; ++k) {
                if (j0 + k < m) {
                    if (k & 1) {
                        acc1.x += b[k].x; acc1.y += b[k].y;
                        acc1.z += b[k].z; acc1.w += b[k].w;
                    } else {
                        acc0.x += b[k].x; acc0.y += b[k].y;
                        acc0.z += b[k].z; acc0.w += b[k].w;
                    }
                }
            }
        }
        for (int k = 32; k < n; ++k) {
            int nk = sorted_nid[beg + k];
            float4 a = feat4[(size_t)nk * 32 + lane];
            acc0.x += a.x; acc0.y += a.y; acc0.z += a.z; acc0.w += a.w;
        }
    }

    float inv = 1.0f / (float)((n > 0) ? n : 1);
    nt4 r;
    r.x = (acc0.x + acc1.x) * inv;
    r.y = (acc0.y + acc1.y) * inv;
    r.z = (acc0.z + acc1.z) * inv;
    r.w = (acc0.w + acc1.w) * inv;
    __builtin_nontemporal_store(
        r, reinterpret_cast<nt4*>(out4) + (size_t)seg * 32 + lane);
}

// ---------------- launch ----------------

extern "C" void kernel_launch(void* const* d_in, const int* in_sizes, int n_in,
                              void* d_out, int out_size, void* d_ws, size_t ws_size,
                              hipStream_t stream) {
    const float* feat = (const float*)d_in[0];
    const int*   nid  = (const int*)d_in[1];
    const int*   sid  = (const int*)d_in[2];
    const int n_edges = in_sizes[1];

    int eb8 = (n_edges + 8 * 256 - 1) / (8 * 256);   // 8 edges/thread
    int rb  = (N_SEG + 7) / 8;

    int* cnt    = RP_CNT(d_ws);
    int* off    = RP_OFF(d_ws);
    int* bsum   = RP_BSUM(d_ws);
    int* rank   = RP_RANK(d_ws);
    int* sorted = RP_SORTED(d_ws);

    hipMemsetAsync(d_ws, 0, (size_t)(1u << 20), stream);

    if (ws_size >= WS_NEED_H) {
        // fp16-table path
        unsigned int* feat16 = (unsigned int*)RP_FEAT16(d_ws);
        int n8 = N_NODES * D_FEAT / 8;     // 1.6M elements of 8 floats
        sp_cvt<<<(n8 + 255) / 256, 256, 0, stream>>>(feat, feat16, n8);
        sp_hist_rank8<<<eb8, 256, 0, stream>>>(sid, cnt, rank, n_edges);
        sp_scan_local<<<SCAN_BLOCKS, 256, 0, stream>>>(cnt, off, bsum);
        sp_scan_blocks<<<1, 256, 0, stream>>>(bsum);
        sp_reorder_rank8<<<eb8, 256, 0, stream>>>(nid, sid, off, bsum, rank,
                                                  sorted, n_edges);
        sp_reduce_h<<<rb, 256, 0, stream>>>((const ushort4*)feat16, sorted,
                                            off, bsum, cnt, (float4*)d_out);
    } else {
        // fp32 fallback path
        sp_hist_rank8<<<eb8, 256, 0, stream>>>(sid, cnt, rank, n_edges);
        sp_scan_local<<<SCAN_BLOCKS, 256, 0, stream>>>(cnt, off, bsum);
        sp_scan_blocks<<<1, 256, 0, stream>>>(bsum);
        sp_reorder_rank8<<<eb8, 256, 0, stream>>>(nid, sid, off, bsum, rank,
                                                  sorted, n_edges);
        sp_reduce<<<rb, 256, 0, stream>>>((const float4*)feat, sorted, off,
                                          bsum, cnt, (float4*)d_out);
    }
}

// Round 6
// 303.734 us; speedup vs baseline: 1.5261x; 1.2322x over previous
//
#include <hip/hip_runtime.h>
#include <hip/hip_fp16.h>

// SubgraphPooling: hierarchical counting sort (all-streaming) + fp16 reduce.
// out[s,:] = mean over edges e with sid[e]==s of feat[nid[e],:]
// N_NODES=100000, D=128, E=2000000, N_SEG=250000
//
// R10 changes vs R9 (374us):
//  - R9 post-mortem: 8x ILP didn't move hist/reorder (~257us) -> they sit at
//    a device-wide random-transaction SERVICE ceiling (~17G/s), not latency.
//  - Replace global-atomic hist + random reorder with a 2-level counting
//    sort whose global traffic is entirely streaming/coalesced:
//      A: coarse count into 489 buckets (s>>9), LDS hist, per-(bucket,block)
//         counts -> no global atomics.
//      scans: per-bucket block-offsets + bucket bases (tiny).
//      B: coarse scatter, LDS-staged so each bucket's run writes out as
//         contiguous packed ints (s&511 | nid) -> coalesced, no atomics.
//      C: fine sort per bucket (512-seg LDS hist + scan, 2 streaming passes)
//         -> emits sorted_nid, beg[s], cnt[s]. LDS atomics only.
//  - No global memset needed (every array fully written).
//  - reduce unchanged (structural floor: 223MB = 8 XCDs x 25.6MB fp16 table),
//    now reads beg/cnt directly.

constexpr int N_NODES = 100000;
constexpr int D_FEAT  = 128;
constexpr int N_SEG   = 250000;

constexpr int BSHIFT     = 9;
constexpr int SEGS_PER_B = 1 << BSHIFT;                        // 512
constexpr int NB         = (N_SEG + SEGS_PER_B - 1) >> BSHIFT; // 489
constexpr int NB_PAD     = 512;
constexpr int EPB        = 8192;                               // edges/block
constexpr int NBLK_MAX   = 256;
constexpr int NID_BITS   = 17;                                 // 100000 < 2^17

// ---- workspace layout ----
// [0,1MB) cnt_g | [1MB,2MB) beg_g | [2MB,+4KB) base | [2MB+64KB,+512KB) cntAB
// [4MB,12MB) pairs | [12MB,20MB) sorted | [20MB,+25.6MB) feat16
#define NP_CNT(ws)    ((int*)((char*)(ws) + 0))
#define NP_BEG(ws)    ((int*)((char*)(ws) + (1u<<20)))
#define NP_BASE(ws)   ((int*)((char*)(ws) + (2u<<20)))
#define NP_CAB(ws)    ((int*)((char*)(ws) + (2u<<20) + (64u<<10)))
#define NP_PAIRS(ws)  ((int*)((char*)(ws) + (4u<<20)))
#define NP_SORT(ws)   ((int*)((char*)(ws) + (12u<<20)))
#define NP_F16(ws)    ((char*)(ws) + (20u<<20))
constexpr size_t FP16_BYTES = (size_t)N_NODES * D_FEAT * 2;          // 25.6 MB
constexpr size_t WS_NEED_H  = (size_t)(20u << 20) + FP16_BYTES;      // ~46.6 MB

// ---- fallback (verified R9) layout ----
#define RP_CNT(ws)     ((int*)((char*)(ws) + 0))
#define RP_OFF(ws)     ((int*)((char*)(ws) + (1u<<20)))
#define RP_BSUM(ws)    ((int*)((char*)(ws) + (2u<<20)))
#define RP_RANK(ws)    ((int*)((char*)(ws) + (4u<<20)))
#define RP_SORTED(ws)  ((int*)((char*)(ws) + (12u<<20)))
constexpr int SCAN_CHUNK  = 1024;
constexpr int SCAN_BLOCKS = (N_SEG + SCAN_CHUNK - 1) / SCAN_CHUNK;  // 245

typedef float nt4 __attribute__((ext_vector_type(4)));
typedef unsigned int ntu4 __attribute__((ext_vector_type(4)));

// ================= new sort pipeline =================

// Pass A: per-block coarse histogram (489 buckets) -> cntAB[b][blk].
__global__ __launch_bounds__(256) void sp_coarse_count(
    const int* __restrict__ sid, int* __restrict__ cntAB, int n)
{
    __shared__ int h[NB_PAD];
    int tid = threadIdx.x;
    for (int i = tid; i < NB_PAD; i += 256) h[i] = 0;
    __syncthreads();
    int e0 = blockIdx.x * EPB;
    int m  = min(EPB, n - e0);
    for (int i = tid; i < m; i += 256)
        atomicAdd(&h[sid[e0 + i] >> BSHIFT], 1);
    __syncthreads();
    for (int b = tid; b < NB; b += 256)
        cntAB[b * NBLK_MAX + blockIdx.x] = h[b];
}

// Scan each bucket's row over blocks (exclusive, in place); base[b] = total.
__global__ __launch_bounds__(256) void sp_scan_ab(
    int* __restrict__ cntAB, int* __restrict__ base, int nblk)
{
    __shared__ int sh[256];
    int b = blockIdx.x, tid = threadIdx.x;
    int* row = cntAB + b * NBLK_MAX;
    int v = (tid < nblk) ? row[tid] : 0;
    sh[tid] = v;
    __syncthreads();
    for (int o = 1; o < 256; o <<= 1) {
        int t = (tid >= o) ? sh[tid - o] : 0;
        __syncthreads();
        sh[tid] += t;
        __syncthreads();
    }
    if (tid < nblk) row[tid] = sh[tid] - v;   // exclusive
    if (tid == 255) base[b] = sh[255];        // bucket total
}

// Exclusive scan of the 489 bucket totals (1 block, 2 entries/thread).
// Also leaves base[NB] = grand total (entries >= NB were 0).
__global__ __launch_bounds__(256) void sp_scan_base(int* __restrict__ base)
{
    __shared__ int sh[256];
    int tid = threadIdx.x;
    int i0 = 2 * tid, i1 = 2 * tid + 1;
    int a = (i0 < NB) ? base[i0] : 0;
    int b = (i1 < NB) ? base[i1] : 0;
    sh[tid] = a + b;
    __syncthreads();
    for (int o = 1; o < 256; o <<= 1) {
        int t = (tid >= o) ? sh[tid - o] : 0;
        __syncthreads();
        sh[tid] += t;
        __syncthreads();
    }
    int excl = (tid > 0) ? sh[tid - 1] : 0;
    base[i0] = excl;        // region is 4KB (1024 ints): safe past NB
    base[i1] = excl + a;
}

// Pass B: coarse scatter. LDS-stage the block's edges grouped by bucket,
// then write each bucket's run contiguously (coalesced, no global atomics).
__global__ __launch_bounds__(256) void sp_coarse_scatter(
    const int* __restrict__ sid, const int* __restrict__ nid,
    const int* __restrict__ cntAB /* exclusive offs */,
    const int* __restrict__ base,
    int* __restrict__ pairs, int n)
{
    __shared__ int hist[NB_PAD];               // counts -> cursors
    __shared__ int dstb[NB_PAD];               // base+offAB-lofs per bucket
    __shared__ int lpair[EPB];                 // packed (slow<<17|nid), 32KB
    __shared__ unsigned short lbuck[EPB];      // bucket per slot, 16KB
    __shared__ int sh[256];
    int tid = threadIdx.x, blk = blockIdx.x;
    int e0 = blk * EPB;
    int m  = min(EPB, n - e0);

    for (int i = tid; i < NB_PAD; i += 256) hist[i] = 0;
    __syncthreads();
    for (int i = tid; i < m; i += 256)
        atomicAdd(&hist[sid[e0 + i] >> BSHIFT], 1);
    __syncthreads();

    // exclusive scan of 512 bucket counts (2/thread)
    int b0 = 2 * tid, b1 = 2 * tid + 1;
    int h0 = hist[b0], h1 = hist[b1];
    sh[tid] = h0 + h1;
    __syncthreads();
    for (int o = 1; o < 256; o <<= 1) {
        int t = (tid >= o) ? sh[tid - o] : 0;
        __syncthreads();
        sh[tid] += t;
        __syncthreads();
    }
    int excl = (tid > 0) ? sh[tid - 1] : 0;
    __syncthreads();                           // everyone done reading hist
    hist[b0] = excl;                           // cursor init = lofs
    hist[b1] = excl + h0;
    dstb[b0] = (b0 < NB) ? (base[b0] + cntAB[b0 * NBLK_MAX + blk] - excl) : 0;
    dstb[b1] = (b1 < NB) ? (base[b1] + cntAB[b1 * NBLK_MAX + blk] - (excl + h0)) : 0;
    __syncthreads();

    // scatter into LDS by bucket
    for (int i = tid; i < m; i += 256) {
        int s = sid[e0 + i], v = nid[e0 + i];
        int b = s >> BSHIFT;
        int r = atomicAdd(&hist[b], 1);
        lpair[r] = ((s & (SEGS_PER_B - 1)) << NID_BITS) | v;
        lbuck[r] = (unsigned short)b;
    }
    __syncthreads();

    // write out: consecutive slots -> consecutive dst within each run
    for (int i = tid; i < m; i += 256)
        pairs[dstb[lbuck[i]] + i] = lpair[i];
}

// Pass C: fine sort within one bucket (512 segments). Two streaming passes
// over the bucket's contiguous pairs; LDS hist + scan; emits sorted/beg/cnt.
__global__ __launch_bounds__(256) void sp_fine_sort(
    const int* __restrict__ pairs, const int* __restrict__ base,
    int* __restrict__ cnt_g, int* __restrict__ beg_g,
    int* __restrict__ sorted)
{
    __shared__ int cnt[SEGS_PER_B];
    __shared__ int cur[SEGS_PER_B];
    __shared__ int sh[256];
    int b = blockIdx.x, tid = threadIdx.x;
    int bstart = base[b];
    int m = base[b + 1] - bstart;

    for (int i = tid; i < SEGS_PER_B; i += 256) cnt[i] = 0;
    __syncthreads();
    for (int i = tid; i < m; i += 256)
        atomicAdd(&cnt[(pairs[bstart + i] >> NID_BITS) & (SEGS_PER_B - 1)], 1);
    __syncthreads();

    int i0 = 2 * tid, i1 = 2 * tid + 1;
    int c0 = cnt[i0], c1 = cnt[i1];
    sh[tid] = c0 + c1;
    __syncthreads();
    for (int o = 1; o < 256; o <<= 1) {
        int t = (tid >= o) ? sh[tid - o] : 0;
        __syncthreads();
        sh[tid] += t;
        __syncthreads();
    }
    int excl = (tid > 0) ? sh[tid - 1] : 0;
    cur[i0] = excl;
    cur[i1] = excl + c0;
    int s0 = (b << BSHIFT) + i0;
    int s1 = s0 + 1;
    if (s0 < N_SEG) { beg_g[s0] = bstart + excl;      cnt_g[s0] = c0; }
    if (s1 < N_SEG) { beg_g[s1] = bstart + excl + c0; cnt_g[s1] = c1; }
    __syncthreads();

    for (int i = tid; i < m; i += 256) {
        int p  = pairs[bstart + i];
        int sl = (p >> NID_BITS) & (SEGS_PER_B - 1);
        int r  = atomicAdd(&cur[sl], 1);
        sorted[bstart + r] = p & ((1 << NID_BITS) - 1);
    }
}

// ================= fp16 table =================

__global__ __launch_bounds__(256) void sp_cvt(
    const float* __restrict__ in, unsigned int* __restrict__ out, int n8)
{
    int i = blockIdx.x * blockDim.x + threadIdx.x;
    if (i >= n8) return;
    const nt4* in4 = (const nt4*)in;
    nt4 v0 = __builtin_nontemporal_load(&in4[2 * i + 0]);
    nt4 v1 = __builtin_nontemporal_load(&in4[2 * i + 1]);
    __half2 h0 = __floats2half2_rn(v0.x, v0.y);
    __half2 h1 = __floats2half2_rn(v0.z, v0.w);
    __half2 h2 = __floats2half2_rn(v1.x, v1.y);
    __half2 h3 = __floats2half2_rn(v1.z, v1.w);
    ntu4 o;
    o.x = *(const unsigned int*)&h0;
    o.y = *(const unsigned int*)&h1;
    o.z = *(const unsigned int*)&h2;
    o.w = *(const unsigned int*)&h3;
    __builtin_nontemporal_store(o, (ntu4*)out + i);
}

__device__ __forceinline__ float2 h2f(unsigned short lo, unsigned short hi)
{
    __half2 h = __halves2half2(__ushort_as_half(lo), __ushort_as_half(hi));
    return __half22float2(h);
}

__device__ __forceinline__ void acc_h(float4& acc, const ushort4& b)
{
    float2 f01 = h2f(b.x, b.y);
    float2 f23 = h2f(b.z, b.w);
    acc.x += f01.x; acc.y += f01.y; acc.z += f23.x; acc.w += f23.y;
}

// Reduce (structural floor): one half-wave per segment, lane = 4 dims (8B).
__global__ __launch_bounds__(256) void sp_reduce_h2(
    const ushort4* __restrict__ feat16,    // [N_NODES][32] ushort4
    const int* __restrict__ sorted_nid,
    const int* __restrict__ beg_g,
    const int* __restrict__ cnt_g,
    float4* __restrict__ out4)             // [N_SEG][32] float4
{
    int seg  = blockIdx.x * 8 + (threadIdx.x >> 5);
    int lane = threadIdx.x & 31;
    if (seg >= N_SEG) return;

    int n   = cnt_g[seg];
    int beg = beg_g[seg];
    int m   = (n < 32) ? n : 32;
    int myid = (lane < m) ? sorted_nid[beg + lane] : 0;

    float4 acc0 = make_float4(0.f, 0.f, 0.f, 0.f);
    float4 acc1 = make_float4(0.f, 0.f, 0.f, 0.f);

    if (m > 0) {
        int last = m - 1;
        for (int j0 = 0; j0 < m; j0 += 8) {
            int id[8];
#pragma unroll
            for (int k = 0; k < 8; ++k) {
                int jj = j0 + k;
                id[k] = __shfl(myid, (jj < last) ? jj : last, 32);
            }
            ushort4 b[8];
#pragma unroll
            for (int k = 0; k < 8; ++k)
                b[k] = feat16[(size_t)id[k] * 32 + lane];
#pragma unroll
            for (int k = 0; k < 8; ++k) {
                if (j0 + k < m) {
                    if (k & 1) acc_h(acc1, b[k]);
                    else       acc_h(acc0, b[k]);
                }
            }
        }
        for (int k = 32; k < n; ++k) {     // pathological n>32 fallback
            int nk = sorted_nid[beg + k];
            acc_h(acc0, feat16[(size_t)nk * 32 + lane]);
        }
    }

    float inv = 1.0f / (float)((n > 0) ? n : 1);
    nt4 r;
    r.x = (acc0.x + acc1.x) * inv;
    r.y = (acc0.y + acc1.y) * inv;
    r.z = (acc0.z + acc1.z) * inv;
    r.w = (acc0.w + acc1.w) * inv;
    __builtin_nontemporal_store(
        r, reinterpret_cast<nt4*>(out4) + (size_t)seg * 32 + lane);
}

// ================= fallback path (verified R9, fp32) =================

__global__ __launch_bounds__(256) void sp_hist_rank(
    const int* __restrict__ sid, int* __restrict__ cnt,
    int* __restrict__ rank, int n)
{
    int i = blockIdx.x * blockDim.x + threadIdx.x;
    if (i >= n) return;
    int s = sid[i];
    rank[i] = atomicAdd(&cnt[s], 1);
}

__global__ __launch_bounds__(256) void sp_scan_local(
    const int* __restrict__ cnt, int* __restrict__ off, int* __restrict__ bsum)
{
    __shared__ int sh[256];
    int tid  = threadIdx.x;
    int base = blockIdx.x * SCAN_CHUNK + tid * 4;
    int v0 = (base + 0 < N_SEG) ? cnt[base + 0] : 0;
    int v1 = (base + 1 < N_SEG) ? cnt[base + 1] : 0;
    int v2 = (base + 2 < N_SEG) ? cnt[base + 2] : 0;
    int v3 = (base + 3 < N_SEG) ? cnt[base + 3] : 0;
    sh[tid] = v0 + v1 + v2 + v3;
    __syncthreads();
    for (int o = 1; o < 256; o <<= 1) {
        int t = (tid >= o) ? sh[tid - o] : 0;
        __syncthreads();
        sh[tid] += t;
        __syncthreads();
    }
    int excl = (tid > 0) ? sh[tid - 1] : 0;
    if (base + 0 < N_SEG) off[base + 0] = excl;
    if (base + 1 < N_SEG) off[base + 1] = excl + v0;
    if (base + 2 < N_SEG) off[base + 2] = excl + v0 + v1;
    if (base + 3 < N_SEG) off[base + 3] = excl + v0 + v1 + v2;
    if (tid == 255) bsum[blockIdx.x] = sh[255];
}

__global__ __launch_bounds__(256) void sp_scan_blocks(int* __restrict__ bsum)
{
    __shared__ int sh[256];
    int tid = threadIdx.x;
    int v = (tid < SCAN_BLOCKS) ? bsum[tid] : 0;
    sh[tid] = v;
    __syncthreads();
    for (int o = 1; o < 256; o <<= 1) {
        int t = (tid >= o) ? sh[tid - o] : 0;
        __syncthreads();
        sh[tid] += t;
        __syncthreads();
    }
    if (tid < SCAN_BLOCKS) bsum[tid] = sh[tid] - v;
}

__global__ __launch_bounds__(256) void sp_reorder_rank(
    const int* __restrict__ nid, const int* __restrict__ sid,
    const int* __restrict__ off, const int* __restrict__ bsum,
    const int* __restrict__ rank, int* __restrict__ sorted_nid, int n)
{
    int i = blockIdx.x * blockDim.x + threadIdx.x;
    if (i >= n) return;
    int s = sid[i];
    sorted_nid[off[s] + bsum[s >> 10] + rank[i]] = nid[i];
}

__global__ __launch_bounds__(256) void sp_reduce(
    const float4* __restrict__ feat4,
    const int* __restrict__ sorted_nid,
    const int* __restrict__ off,
    const int* __restrict__ bsum,
    const int* __restrict__ cnt,
    float4* __restrict__ out4)
{
    int seg  = blockIdx.x * 8 + (threadIdx.x >> 5);
    int lane = threadIdx.x & 31;
    if (seg >= N_SEG) return;

    int n   = cnt[seg];
    int beg = off[seg] + bsum[seg >> 10];
    int m   = (n < 32) ? n : 32;
    int myid = (lane < m) ? sorted_nid[beg + lane] : 0;

    float4 acc0 = make_float4(0.f, 0.f, 0.f, 0.f);
    float4 acc1 = make_float4(0.f, 0.f, 0.f, 0.f);

    if (m > 0) {
        int last = m - 1;
        for (int j0 = 0; j0 < m; j0 += 8) {
            int id[8];
#pragma unroll
            for (int k = 0; k < 8; ++k) {
                int jj = j0 + k;
                id[k] = __shfl(myid, (jj < last) ? jj : last, 32);
            }
            float4 b[8];
#pragma unroll
            for (int k = 0; k < 8; ++k)
                b[k] = feat4[(size_t)id[k] * 32 + lane];
#pragma unroll
            for (int k = 0; k < 8; ++k) {
                if (j0 + k < m) {
                    if (k & 1) {
                        acc1.x += b[k].x; acc1.y += b[k].y;
                        acc1.z += b[k].z; acc1.w += b[k].w;
                    } else {
                        acc0.x += b[k].x; acc0.y += b[k].y;
                        acc0.z += b[k].z; acc0.w += b[k].w;
                    }
                }
            }
        }
        for (int k = 32; k < n; ++k) {
            int nk = sorted_nid[beg + k];
            float4 a = feat4[(size_t)nk * 32 + lane];
            acc0.x += a.x; acc0.y += a.y; acc0.z += a.z; acc0.w += a.w;
        }
    }

    float inv = 1.0f / (float)((n > 0) ? n : 1);
    nt4 r;
    r.x = (acc0.x + acc1.x) * inv;
    r.y = (acc0.y + acc1.y) * inv;
    r.z = (acc0.z + acc1.z) * inv;
    r.w = (acc0.w + acc1.w) * inv;
    __builtin_nontemporal_store(
        r, reinterpret_cast<nt4*>(out4) + (size_t)seg * 32 + lane);
}

// ================= launch =================

extern "C" void kernel_launch(void* const* d_in, const int* in_sizes, int n_in,
                              void* d_out, int out_size, void* d_ws, size_t ws_size,
                              hipStream_t stream) {
    const float* feat = (const float*)d_in[0];
    const int*   nid  = (const int*)d_in[1];
    const int*   sid  = (const int*)d_in[2];
    const int n_edges = in_sizes[1];

    int nblk = (n_edges + EPB - 1) / EPB;
    int rb   = (N_SEG + 7) / 8;

    if (ws_size >= WS_NEED_H && nblk <= NBLK_MAX && n_edges > 0) {
        // hierarchical streaming sort + fp16 reduce
        int* cnt_g  = NP_CNT(d_ws);
        int* beg_g  = NP_BEG(d_ws);
        int* base   = NP_BASE(d_ws);
        int* cntAB  = NP_CAB(d_ws);
        int* pairs  = NP_PAIRS(d_ws);
        int* sorted = NP_SORT(d_ws);
        unsigned int* feat16 = (unsigned int*)NP_F16(d_ws);

        int n8 = N_NODES * D_FEAT / 8;
        sp_cvt<<<(n8 + 255) / 256, 256, 0, stream>>>(feat, feat16, n8);
        sp_coarse_count<<<nblk, 256, 0, stream>>>(sid, cntAB, n_edges);
        sp_scan_ab<<<NB, 256, 0, stream>>>(cntAB, base, nblk);
        sp_scan_base<<<1, 256, 0, stream>>>(base);
        sp_coarse_scatter<<<nblk, 256, 0, stream>>>(sid, nid, cntAB, base,
                                                    pairs, n_edges);
        sp_fine_sort<<<NB, 256, 0, stream>>>(pairs, base, cnt_g, beg_g,
                                             sorted);
        sp_reduce_h2<<<rb, 256, 0, stream>>>((const ushort4*)feat16, sorted,
                                             beg_g, cnt_g, (float4*)d_out);
    } else {
        // fallback: verified fp32 rank path
        int* cnt    = RP_CNT(d_ws);
        int* off    = RP_OFF(d_ws);
        int* bsum   = RP_BSUM(d_ws);
        int* rank   = RP_RANK(d_ws);
        int* sorted = RP_SORTED(d_ws);
        int eb = (n_edges + 255) / 256;

        hipMemsetAsync(d_ws, 0, (size_t)(1u << 20), stream);
        sp_hist_rank<<<eb, 256, 0, stream>>>(sid, cnt, rank, n_edges);
        sp_scan_local<<<SCAN_BLOCKS, 256, 0, stream>>>(cnt, off, bsum);
        sp_scan_blocks<<<1, 256, 0, stream>>>(bsum);
        sp_reorder_rank<<<eb, 256, 0, stream>>>(nid, sid, off, bsum, rank,
                                                sorted, n_edges);
        sp_reduce<<<rb, 256, 0, stream>>>((const float4*)feat, sorted, off,
                                          bsum, cnt, (float4*)d_out);
    }
}

// Round 7
// 293.443 us; speedup vs baseline: 1.5796x; 1.0351x over previous
//
#include <hip/hip_runtime.h>
#include <hip/hip_fp16.h>

// SubgraphPooling: hierarchical counting sort (all-streaming) + fp16 reduce.
// out[s,:] = mean over edges e with sid[e]==s of feat[nid[e],:]
// N_NODES=100000, D=128, E=2000000, N_SEG=250000
//
// R11 changes vs R10 (304us):
//  - R10 post-mortem: sort side ~215us for ~50MB of traffic -> occupancy-
//    starved (grids of 245-489 blocks, <=1 block/CU, 1 wave/SIMD).
//  - EPB 8192->4096 with 512-thread blocks: coarse passes now 489 blocks
//    x 8 waves (~16 waves/CU, 8x wave count).
//  - BSHIFT 9->8: 977 buckets of 256 segs (~2048 edges each); fine_sort
//    grid 489->977 (~4 blocks/CU); smaller serial work per block.
//  - cntAB = 977x512x4 = 1.9MB, same 46.6MB workspace bound.
//  - reduce unchanged (structural floor: 223MB = 8 XCDs x 25.6MB table).

constexpr int N_NODES = 100000;
constexpr int D_FEAT  = 128;
constexpr int N_SEG   = 250000;

constexpr int BSHIFT     = 8;
constexpr int SEGS_PER_B = 1 << BSHIFT;                        // 256
constexpr int NB         = (N_SEG + SEGS_PER_B - 1) >> BSHIFT; // 977
constexpr int NB_PAD     = 1024;
constexpr int EPB        = 4096;                               // edges/block
constexpr int NBLK_MAX   = 512;
constexpr int CTH        = 512;                                // coarse threads
constexpr int NID_BITS   = 17;                                 // 100000 < 2^17

// ---- workspace layout ----
// [0,1MB) cnt_g | [1MB,2MB) beg_g | [2MB,+8KB) base
// [2MB+16KB, +1.91MB) cntAB | [4MB,12MB) pairs | [12MB,20MB) sorted
// [20MB,+25.6MB) feat16
#define NP_CNT(ws)    ((int*)((char*)(ws) + 0))
#define NP_BEG(ws)    ((int*)((char*)(ws) + (1u<<20)))
#define NP_BASE(ws)   ((int*)((char*)(ws) + (2u<<20)))
#define NP_CAB(ws)    ((int*)((char*)(ws) + (2u<<20) + (16u<<10)))
#define NP_PAIRS(ws)  ((int*)((char*)(ws) + (4u<<20)))
#define NP_SORT(ws)   ((int*)((char*)(ws) + (12u<<20)))
#define NP_F16(ws)    ((char*)(ws) + (20u<<20))
constexpr size_t FP16_BYTES = (size_t)N_NODES * D_FEAT * 2;          // 25.6 MB
constexpr size_t WS_NEED_H  = (size_t)(20u << 20) + FP16_BYTES;      // ~46.6 MB

// ---- fallback (verified R9) layout ----
#define RP_CNT(ws)     ((int*)((char*)(ws) + 0))
#define RP_OFF(ws)     ((int*)((char*)(ws) + (1u<<20)))
#define RP_BSUM(ws)    ((int*)((char*)(ws) + (2u<<20)))
#define RP_RANK(ws)    ((int*)((char*)(ws) + (4u<<20)))
#define RP_SORTED(ws)  ((int*)((char*)(ws) + (12u<<20)))
constexpr int SCAN_CHUNK  = 1024;
constexpr int SCAN_BLOCKS = (N_SEG + SCAN_CHUNK - 1) / SCAN_CHUNK;  // 245

typedef float nt4 __attribute__((ext_vector_type(4)));
typedef unsigned int ntu4 __attribute__((ext_vector_type(4)));

// ================= sort pipeline =================

// Pass A: per-block coarse histogram (977 buckets) -> cntAB[b][blk].
__global__ __launch_bounds__(CTH) void sp_coarse_count(
    const int* __restrict__ sid, int* __restrict__ cntAB, int n)
{
    __shared__ int h[NB_PAD];
    int tid = threadIdx.x;
    for (int i = tid; i < NB_PAD; i += CTH) h[i] = 0;
    __syncthreads();
    int e0 = blockIdx.x * EPB;
    int m  = min(EPB, n - e0);
    for (int i = tid; i < m; i += CTH)
        atomicAdd(&h[sid[e0 + i] >> BSHIFT], 1);
    __syncthreads();
    for (int b = tid; b < NB; b += CTH)
        cntAB[b * NBLK_MAX + blockIdx.x] = h[b];
}

// Scan each bucket's row over blocks (exclusive, in place); base[b] = total.
// 256 threads, 2 entries/thread (NBLK_MAX = 512).
__global__ __launch_bounds__(256) void sp_scan_ab(
    int* __restrict__ cntAB, int* __restrict__ base, int nblk)
{
    __shared__ int sh[256];
    int b = blockIdx.x, tid = threadIdx.x;
    int* row = cntAB + b * NBLK_MAX;
    int i0 = 2 * tid, i1 = 2 * tid + 1;
    int v0 = (i0 < nblk) ? row[i0] : 0;
    int v1 = (i1 < nblk) ? row[i1] : 0;
    sh[tid] = v0 + v1;
    __syncthreads();
    for (int o = 1; o < 256; o <<= 1) {
        int t = (tid >= o) ? sh[tid - o] : 0;
        __syncthreads();
        sh[tid] += t;
        __syncthreads();
    }
    int excl = (tid > 0) ? sh[tid - 1] : 0;
    row[i0] = excl;
    row[i1] = excl + v0;
    if (tid == 255) base[b] = sh[255];        // bucket total
}

// Exclusive scan of the 977 bucket totals (1 block, 4 entries/thread).
// Leaves base[NB] = grand total.
__global__ __launch_bounds__(256) void sp_scan_base(int* __restrict__ base)
{
    __shared__ int sh[256];
    int tid = threadIdx.x;
    int i0 = 4 * tid;
    int a0 = (i0 + 0 < NB) ? base[i0 + 0] : 0;
    int a1 = (i0 + 1 < NB) ? base[i0 + 1] : 0;
    int a2 = (i0 + 2 < NB) ? base[i0 + 2] : 0;
    int a3 = (i0 + 3 < NB) ? base[i0 + 3] : 0;
    sh[tid] = a0 + a1 + a2 + a3;
    __syncthreads();
    for (int o = 1; o < 256; o <<= 1) {
        int t = (tid >= o) ? sh[tid - o] : 0;
        __syncthreads();
        sh[tid] += t;
        __syncthreads();
    }
    int excl = (tid > 0) ? sh[tid - 1] : 0;
    base[i0 + 0] = excl;                 // region is 8KB: safe past NB
    base[i0 + 1] = excl + a0;
    base[i0 + 2] = excl + a0 + a1;
    base[i0 + 3] = excl + a0 + a1 + a2;
}

// Pass B: coarse scatter. LDS-stage the block's edges grouped by bucket,
// then write each bucket's run contiguously (coalesced, no global atomics).
__global__ __launch_bounds__(CTH) void sp_coarse_scatter(
    const int* __restrict__ sid, const int* __restrict__ nid,
    const int* __restrict__ cntAB /* exclusive offs */,
    const int* __restrict__ base,
    int* __restrict__ pairs, int n)
{
    __shared__ int hist[NB_PAD];               // counts -> cursors
    __shared__ int dstb[NB_PAD];               // base+offAB-lofs per bucket
    __shared__ int lpair[EPB];                 // packed (slow<<17|nid), 16KB
    __shared__ unsigned short lbuck[EPB];      // bucket per slot, 8KB
    __shared__ int sh[CTH];
    int tid = threadIdx.x, blk = blockIdx.x;
    int e0 = blk * EPB;
    int m  = min(EPB, n - e0);

    for (int i = tid; i < NB_PAD; i += CTH) hist[i] = 0;
    __syncthreads();
    for (int i = tid; i < m; i += CTH)
        atomicAdd(&hist[sid[e0 + i] >> BSHIFT], 1);
    __syncthreads();

    // exclusive scan of 1024 bucket counts (2/thread over 512 threads)
    int b0 = 2 * tid, b1 = 2 * tid + 1;
    int h0 = hist[b0], h1 = hist[b1];
    sh[tid] = h0 + h1;
    __syncthreads();
    for (int o = 1; o < CTH; o <<= 1) {
        int t = (tid >= o) ? sh[tid - o] : 0;
        __syncthreads();
        sh[tid] += t;
        __syncthreads();
    }
    int excl = (tid > 0) ? sh[tid - 1] : 0;
    __syncthreads();                           // all reads of hist done
    hist[b0] = excl;                           // cursor init = lofs
    hist[b1] = excl + h0;
    dstb[b0] = (b0 < NB) ? (base[b0] + cntAB[b0 * NBLK_MAX + blk] - excl) : 0;
    dstb[b1] = (b1 < NB) ? (base[b1] + cntAB[b1 * NBLK_MAX + blk] - (excl + h0)) : 0;
    __syncthreads();

    // scatter into LDS by bucket
    for (int i = tid; i < m; i += CTH) {
        int s = sid[e0 + i], v = nid[e0 + i];
        int b = s >> BSHIFT;
        int r = atomicAdd(&hist[b], 1);
        lpair[r] = ((s & (SEGS_PER_B - 1)) << NID_BITS) | v;
        lbuck[r] = (unsigned short)b;
    }
    __syncthreads();

    // write out: consecutive slots -> consecutive dst within each run
    for (int i = tid; i < m; i += CTH)
        pairs[dstb[lbuck[i]] + i] = lpair[i];
}

// Pass C: fine sort within one bucket (256 segments, ~2048 edges). Two
// streaming passes (2nd read is L2-hot); LDS hist + scan; emits
// sorted/beg/cnt. LDS atomics only.
__global__ __launch_bounds__(256) void sp_fine_sort(
    const int* __restrict__ pairs, const int* __restrict__ base,
    int* __restrict__ cnt_g, int* __restrict__ beg_g,
    int* __restrict__ sorted)
{
    __shared__ int cnt[SEGS_PER_B];
    __shared__ int cur[SEGS_PER_B];
    __shared__ int sh[256];
    int b = blockIdx.x, tid = threadIdx.x;
    int bstart = base[b];
    int m = base[b + 1] - bstart;

    cnt[tid] = 0;
    __syncthreads();
    for (int i = tid; i < m; i += 256)
        atomicAdd(&cnt[(pairs[bstart + i] >> NID_BITS) & (SEGS_PER_B - 1)], 1);
    __syncthreads();

    int c = cnt[tid];
    sh[tid] = c;
    __syncthreads();
    for (int o = 1; o < 256; o <<= 1) {
        int t = (tid >= o) ? sh[tid - o] : 0;
        __syncthreads();
        sh[tid] += t;
        __syncthreads();
    }
    int excl = sh[tid] - c;
    cur[tid] = excl;
    int s = (b << BSHIFT) + tid;
    if (s < N_SEG) { beg_g[s] = bstart + excl; cnt_g[s] = c; }
    __syncthreads();

    for (int i = tid; i < m; i += 256) {
        int p  = pairs[bstart + i];
        int sl = (p >> NID_BITS) & (SEGS_PER_B - 1);
        int r  = atomicAdd(&cur[sl], 1);
        sorted[bstart + r] = p & ((1 << NID_BITS) - 1);
    }
}

// ================= fp16 table =================

__global__ __launch_bounds__(256) void sp_cvt(
    const float* __restrict__ in, unsigned int* __restrict__ out, int n8)
{
    int i = blockIdx.x * blockDim.x + threadIdx.x;
    if (i >= n8) return;
    const nt4* in4 = (const nt4*)in;
    nt4 v0 = __builtin_nontemporal_load(&in4[2 * i + 0]);
    nt4 v1 = __builtin_nontemporal_load(&in4[2 * i + 1]);
    __half2 h0 = __floats2half2_rn(v0.x, v0.y);
    __half2 h1 = __floats2half2_rn(v0.z, v0.w);
    __half2 h2 = __floats2half2_rn(v1.x, v1.y);
    __half2 h3 = __floats2half2_rn(v1.z, v1.w);
    ntu4 o;
    o.x = *(const unsigned int*)&h0;
    o.y = *(const unsigned int*)&h1;
    o.z = *(const unsigned int*)&h2;
    o.w = *(const unsigned int*)&h3;
    __builtin_nontemporal_store(o, (ntu4*)out + i);
}

__device__ __forceinline__ float2 h2f(unsigned short lo, unsigned short hi)
{
    __half2 h = __halves2half2(__ushort_as_half(lo), __ushort_as_half(hi));
    return __half22float2(h);
}

__device__ __forceinline__ void acc_h(float4& acc, const ushort4& b)
{
    float2 f01 = h2f(b.x, b.y);
    float2 f23 = h2f(b.z, b.w);
    acc.x += f01.x; acc.y += f01.y; acc.z += f23.x; acc.w += f23.y;
}

// Reduce (structural floor): one half-wave per segment, lane = 4 dims (8B).
__global__ __launch_bounds__(256) void sp_reduce_h2(
    const ushort4* __restrict__ feat16,    // [N_NODES][32] ushort4
    const int* __restrict__ sorted_nid,
    const int* __restrict__ beg_g,
    const int* __restrict__ cnt_g,
    float4* __restrict__ out4)             // [N_SEG][32] float4
{
    int seg  = blockIdx.x * 8 + (threadIdx.x >> 5);
    int lane = threadIdx.x & 31;
    if (seg >= N_SEG) return;

    int n   = cnt_g[seg];
    int beg = beg_g[seg];
    int m   = (n < 32) ? n : 32;
    int myid = (lane < m) ? sorted_nid[beg + lane] : 0;

    float4 acc0 = make_float4(0.f, 0.f, 0.f, 0.f);
    float4 acc1 = make_float4(0.f, 0.f, 0.f, 0.f);

    if (m > 0) {
        int last = m - 1;
        for (int j0 = 0; j0 < m; j0 += 8) {
            int id[8];
#pragma unroll
            for (int k = 0; k < 8; ++k) {
                int jj = j0 + k;
                id[k] = __shfl(myid, (jj < last) ? jj : last, 32);
            }
            ushort4 b[8];
#pragma unroll
            for (int k = 0; k < 8; ++k)
                b[k] = feat16[(size_t)id[k] * 32 + lane];
#pragma unroll
            for (int k = 0; k < 8; ++k) {
                if (j0 + k < m) {
                    if (k & 1) acc_h(acc1, b[k]);
                    else       acc_h(acc0, b[k]);
                }
            }
        }
        for (int k = 32; k < n; ++k) {     // pathological n>32 fallback
            int nk = sorted_nid[beg + k];
            acc_h(acc0, feat16[(size_t)nk * 32 + lane]);
        }
    }

    float inv = 1.0f / (float)((n > 0) ? n : 1);
    nt4 r;
    r.x = (acc0.x + acc1.x) * inv;
    r.y = (acc0.y + acc1.y) * inv;
    r.z = (acc0.z + acc1.z) * inv;
    r.w = (acc0.w + acc1.w) * inv;
    __builtin_nontemporal_store(
        r, reinterpret_cast<nt4*>(out4) + (size_t)seg * 32 + lane);
}

// ================= fallback path (verified R9, fp32) =================

__global__ __launch_bounds__(256) void sp_hist_rank(
    const int* __restrict__ sid, int* __restrict__ cnt,
    int* __restrict__ rank, int n)
{
    int i = blockIdx.x * blockDim.x + threadIdx.x;
    if (i >= n) return;
    int s = sid[i];
    rank[i] = atomicAdd(&cnt[s], 1);
}

__global__ __launch_bounds__(256) void sp_scan_local(
    const int* __restrict__ cnt, int* __restrict__ off, int* __restrict__ bsum)
{
    __shared__ int sh[256];
    int tid  = threadIdx.x;
    int base = blockIdx.x * SCAN_CHUNK + tid * 4;
    int v0 = (base + 0 < N_SEG) ? cnt[base + 0] : 0;
    int v1 = (base + 1 < N_SEG) ? cnt[base + 1] : 0;
    int v2 = (base + 2 < N_SEG) ? cnt[base + 2] : 0;
    int v3 = (base + 3 < N_SEG) ? cnt[base + 3] : 0;
    sh[tid] = v0 + v1 + v2 + v3;
    __syncthreads();
    for (int o = 1; o < 256; o <<= 1) {
        int t = (tid >= o) ? sh[tid - o] : 0;
        __syncthreads();
        sh[tid] += t;
        __syncthreads();
    }
    int excl = (tid > 0) ? sh[tid - 1] : 0;
    if (base + 0 < N_SEG) off[base + 0] = excl;
    if (base + 1 < N_SEG) off[base + 1] = excl + v0;
    if (base + 2 < N_SEG) off[base + 2] = excl + v0 + v1;
    if (base + 3 < N_SEG) off[base + 3] = excl + v0 + v1 + v2;
    if (tid == 255) bsum[blockIdx.x] = sh[255];
}

__global__ __launch_bounds__(256) void sp_scan_blocks(int* __restrict__ bsum)
{
    __shared__ int sh[256];
    int tid = threadIdx.x;
    int v = (tid < SCAN_BLOCKS) ? bsum[tid] : 0;
    sh[tid] = v;
    __syncthreads();
    for (int o = 1; o < 256; o <<= 1) {
        int t = (tid >= o) ? sh[tid - o] : 0;
        __syncthreads();
        sh[tid] += t;
        __syncthreads();
    }
    if (tid < SCAN_BLOCKS) bsum[tid] = sh[tid] - v;
}

__global__ __launch_bounds__(256) void sp_reorder_rank(
    const int* __restrict__ nid, const int* __restrict__ sid,
    const int* __restrict__ off, const int* __restrict__ bsum,
    const int* __restrict__ rank, int* __restrict__ sorted_nid, int n)
{
    int i = blockIdx.x * blockDim.x + threadIdx.x;
    if (i >= n) return;
    int s = sid[i];
    sorted_nid[off[s] + bsum[s >> 10] + rank[i]] = nid[i];
}

__global__ __launch_bounds__(256) void sp_reduce(
    const float4* __restrict__ feat4,
    const int* __restrict__ sorted_nid,
    const int* __restrict__ off,
    const int* __restrict__ bsum,
    const int* __restrict__ cnt,
    float4* __restrict__ out4)
{
    int seg  = blockIdx.x * 8 + (threadIdx.x >> 5);
    int lane = threadIdx.x & 31;
    if (seg >= N_SEG) return;

    int n   = cnt[seg];
    int beg = off[seg] + bsum[seg >> 10];
    int m   = (n < 32) ? n : 32;
    int myid = (lane < m) ? sorted_nid[beg + lane] : 0;

    float4 acc0 = make_float4(0.f, 0.f, 0.f, 0.f);
    float4 acc1 = make_float4(0.f, 0.f, 0.f, 0.f);

    if (m > 0) {
        int last = m - 1;
        for (int j0 = 0; j0 < m; j0 += 8) {
            int id[8];
#pragma unroll
            for (int k = 0; k < 8; ++k) {
                int jj = j0 + k;
                id[k] = __shfl(myid, (jj < last) ? jj : last, 32);
            }
            float4 b[8];
#pragma unroll
            for (int k = 0; k < 8; ++k)
                b[k] = feat4[(size_t)id[k] * 32 + lane];
#pragma unroll
            for (int k = 0; k < 8; ++k) {
                if (j0 + k < m) {
                    if (k & 1) {
                        acc1.x += b[k].x; acc1.y += b[k].y;
                        acc1.z += b[k].z; acc1.w += b[k].w;
                    } else {
                        acc0.x += b[k].x; acc0.y += b[k].y;
                        acc0.z += b[k].z; acc0.w += b[k].w;
                    }
                }
            }
        }
        for (int k = 32; k < n; ++k) {
            int nk = sorted_nid[beg + k];
            float4 a = feat4[(size_t)nk * 32 + lane];
            acc0.x += a.x; acc0.y += a.y; acc0.z += a.z; acc0.w += a.w;
        }
    }

    float inv = 1.0f / (float)((n > 0) ? n : 1);
    nt4 r;
    r.x = (acc0.x + acc1.x) * inv;
    r.y = (acc0.y + acc1.y) * inv;
    r.z = (acc0.z + acc1.z) * inv;
    r.w = (acc0.w + acc1.w) * inv;
    __builtin_nontemporal_store(
        r, reinterpret_cast<nt4*>(out4) + (size_t)seg * 32 + lane);
}

// ================= launch =================

extern "C" void kernel_launch(void* const* d_in, const int* in_sizes, int n_in,
                              void* d_out, int out_size, void* d_ws, size_t ws_size,
                              hipStream_t stream) {
    const float* feat = (const float*)d_in[0];
    const int*   nid  = (const int*)d_in[1];
    const int*   sid  = (const int*)d_in[2];
    const int n_edges = in_sizes[1];

    int nblk = (n_edges + EPB - 1) / EPB;
    int rb   = (N_SEG + 7) / 8;

    if (ws_size >= WS_NEED_H && nblk <= NBLK_MAX && n_edges > 0) {
        // hierarchical streaming sort + fp16 reduce
        int* cnt_g  = NP_CNT(d_ws);
        int* beg_g  = NP_BEG(d_ws);
        int* base   = NP_BASE(d_ws);
        int* cntAB  = NP_CAB(d_ws);
        int* pairs  = NP_PAIRS(d_ws);
        int* sorted = NP_SORT(d_ws);
        unsigned int* feat16 = (unsigned int*)NP_F16(d_ws);

        int n8 = N_NODES * D_FEAT / 8;
        sp_cvt<<<(n8 + 255) / 256, 256, 0, stream>>>(feat, feat16, n8);
        sp_coarse_count<<<nblk, CTH, 0, stream>>>(sid, cntAB, n_edges);
        sp_scan_ab<<<NB, 256, 0, stream>>>(cntAB, base, nblk);
        sp_scan_base<<<1, 256, 0, stream>>>(base);
        sp_coarse_scatter<<<nblk, CTH, 0, stream>>>(sid, nid, cntAB, base,
                                                    pairs, n_edges);
        sp_fine_sort<<<NB, 256, 0, stream>>>(pairs, base, cnt_g, beg_g,
                                             sorted);
        sp_reduce_h2<<<rb, 256, 0, stream>>>((const ushort4*)feat16, sorted,
                                             beg_g, cnt_g, (float4*)d_out);
    } else {
        // fallback: verified fp32 rank path
        int* cnt    = RP_CNT(d_ws);
        int* off    = RP_OFF(d_ws);
        int* bsum   = RP_BSUM(d_ws);
        int* rank   = RP_RANK(d_ws);
        int* sorted = RP_SORTED(d_ws);
        int eb = (n_edges + 255) / 256;

        hipMemsetAsync(d_ws, 0, (size_t)(1u << 20), stream);
        sp_hist_rank<<<eb, 256, 0, stream>>>(sid, cnt, rank, n_edges);
        sp_scan_local<<<SCAN_BLOCKS, 256, 0, stream>>>(cnt, off, bsum);
        sp_scan_blocks<<<1, 256, 0, stream>>>(bsum);
        sp_reorder_rank<<<eb, 256, 0, stream>>>(nid, sid, off, bsum, rank,
                                                sorted, n_edges);
        sp_reduce<<<rb, 256, 0, stream>>>((const float4*)feat, sorted, off,
                                          bsum, cnt, (float4*)d_out);
    }
}

// Round 8
// 288.754 us; speedup vs baseline: 1.6053x; 1.0162x over previous
//
#include <hip/hip_runtime.h>
#include <hip/hip_fp16.h>

// SubgraphPooling: padded-bucket scatter + fused bucket-sort/reduce (fp16).
// out[s,:] = mean over edges e with sid[e]==s of feat[nid[e],:]
// N_NODES=100000, D=128, E=2000000, N_SEG=250000
//
// R12 changes vs R11 (293us):
//  - Mean is permutation-invariant -> within-bucket edge order is free.
//    Replace exact 2-level allocation (count+scan+scan+scatter+fine_sort,
//    5 dispatches, cntAB cross-XCD false sharing) with PADDED bucket
//    regions (CAP_B=4096, expected fill 2048+-45): one kernel does
//    LDS-group + ONE global atomicAdd per (block,bucket) (~239K atomics
//    vs 2M) + ~34B-run writes (~250K transactions vs 2M).
//  - fine_sort fused INTO the reduce: per-bucket LDS hist/scan/scatter
//    prologue (~1us), then the identical half-wave gather. Kills 16MB of
//    sorted traffic + a dispatch.
//  - Overflow (bucket>4096, 45 sigma away) goes to an exact global list
//    drained in-kernel -> correct for any data.
//  - 4 dispatches total (memset, cvt, scatter, reduce).

constexpr int N_NODES = 100000;
constexpr int D_FEAT  = 128;
constexpr int N_SEG   = 250000;

constexpr int BSHIFT     = 8;
constexpr int SEGS_PER_B = 1 << BSHIFT;                        // 256
constexpr int NB         = (N_SEG + SEGS_PER_B - 1) >> BSHIFT; // 977
constexpr int NB_PAD     = 1024;
constexpr int EPB        = 8192;                               // edges/block
constexpr int CTH        = 512;
constexpr int CAP_B      = 4096;                               // slots/bucket
constexpr int NID_BITS   = 17;                                 // 100000 < 2^17
constexpr int NID_MASK   = (1 << NID_BITS) - 1;
constexpr int OVF_CAP    = 262144;

// ---- workspace layout ----
// [0, 3908)        cursor[NB]          (zeroed)
// [4096, 4100)     ovf_cnt             (zeroed)
// [1MB, 1MB+15.3MB) pairs  int[NB*CAP_B]
// [18MB, 20MB)     ovf    int2[OVF_CAP]
// [20MB, +25.6MB)  feat16
#define NP_CUR(ws)    ((int*)((char*)(ws) + 0))
#define NP_OVFC(ws)   ((int*)((char*)(ws) + 4096))
#define NP_PAIRS(ws)  ((int*)((char*)(ws) + (1u<<20)))
#define NP_OVF(ws)    ((int2*)((char*)(ws) + (18u<<20)))
#define NP_F16(ws)    ((char*)(ws) + (20u<<20))
constexpr size_t FP16_BYTES = (size_t)N_NODES * D_FEAT * 2;          // 25.6 MB
constexpr size_t WS_NEED_H  = (size_t)(20u << 20) + FP16_BYTES;      // ~46.6 MB

// ---- fallback (verified fp32 rank path) layout ----
#define RP_CNT(ws)     ((int*)((char*)(ws) + 0))
#define RP_OFF(ws)     ((int*)((char*)(ws) + (1u<<20)))
#define RP_BSUM(ws)    ((int*)((char*)(ws) + (2u<<20)))
#define RP_RANK(ws)    ((int*)((char*)(ws) + (4u<<20)))
#define RP_SORTED(ws)  ((int*)((char*)(ws) + (12u<<20)))
constexpr int SCAN_CHUNK  = 1024;
constexpr int SCAN_BLOCKS = (N_SEG + SCAN_CHUNK - 1) / SCAN_CHUNK;  // 245

typedef float nt4 __attribute__((ext_vector_type(4)));
typedef unsigned int ntu4 __attribute__((ext_vector_type(4)));

// ================= bucket scatter (one pass, padded regions) =============

__global__ __launch_bounds__(CTH) void sp_bucket_scatter(
    const int* __restrict__ sid, const int* __restrict__ nid,
    int* __restrict__ cursor_g, int* __restrict__ pairs,
    int* __restrict__ ovf_cnt, int2* __restrict__ ovf, int n)
{
    __shared__ int hist[NB_PAD];               // counts -> LDS cursors
    __shared__ int dstb[NB_PAD];               // global base - local offset
    __shared__ int lpair[EPB];                 // packed (slow<<17|nid), 32KB
    __shared__ unsigned short lbuck[EPB];      // bucket per slot, 16KB
    __shared__ int sh[CTH];
    int tid = threadIdx.x;
    int e0  = blockIdx.x * EPB;
    int m   = min(EPB, n - e0);

    for (int i = tid; i < NB_PAD; i += CTH) hist[i] = 0;
    __syncthreads();
    for (int i = tid; i < m; i += CTH)
        atomicAdd(&hist[sid[e0 + i] >> BSHIFT], 1);
    __syncthreads();

    // exclusive scan of 1024 bucket counts (2/thread over 512 threads)
    int b0 = 2 * tid, b1 = 2 * tid + 1;
    int h0 = hist[b0], h1 = hist[b1];
    sh[tid] = h0 + h1;
    __syncthreads();
    for (int o = 1; o < CTH; o <<= 1) {
        int t = (tid >= o) ? sh[tid - o] : 0;
        __syncthreads();
        sh[tid] += t;
        __syncthreads();
    }
    int excl = (tid > 0) ? sh[tid - 1] : 0;
    __syncthreads();                           // all reads of hist done
    hist[b0] = excl;                           // LDS scatter cursors
    hist[b1] = excl + h0;
    // allocate this block's run in each bucket's padded region
    int a0 = (b0 < NB && h0 > 0) ? atomicAdd(&cursor_g[b0], h0) : 0;
    int a1 = (b1 < NB && h1 > 0) ? atomicAdd(&cursor_g[b1], h1) : 0;
    dstb[b0] = a0 - excl;
    dstb[b1] = a1 - (excl + h0);
    __syncthreads();

    // group into LDS by bucket
    for (int i = tid; i < m; i += CTH) {
        int s = sid[e0 + i], v = nid[e0 + i];
        int b = s >> BSHIFT;
        int r = atomicAdd(&hist[b], 1);
        lpair[r] = ((s & (SEGS_PER_B - 1)) << NID_BITS) | v;
        lbuck[r] = (unsigned short)b;
    }
    __syncthreads();

    // write out: each bucket's run lands contiguously in its padded region
    for (int i = tid; i < m; i += CTH) {
        int b  = lbuck[i];
        int p  = dstb[b] + i;                  // position within bucket
        int pk = lpair[i];
        if (p < CAP_B) {
            pairs[b * CAP_B + p] = pk;
        } else {                               // 45-sigma overflow: exact list
            int o = atomicAdd(ovf_cnt, 1);
            if (o < OVF_CAP)
                ovf[o] = make_int2((b << BSHIFT) | (pk >> NID_BITS),
                                   pk & NID_MASK);
        }
    }
}

// ================= fp16 table =================

__global__ __launch_bounds__(256) void sp_cvt(
    const float* __restrict__ in, unsigned int* __restrict__ out, int n8)
{
    int i = blockIdx.x * blockDim.x + threadIdx.x;
    if (i >= n8) return;
    const nt4* in4 = (const nt4*)in;
    nt4 v0 = __builtin_nontemporal_load(&in4[2 * i + 0]);
    nt4 v1 = __builtin_nontemporal_load(&in4[2 * i + 1]);
    __half2 h0 = __floats2half2_rn(v0.x, v0.y);
    __half2 h1 = __floats2half2_rn(v0.z, v0.w);
    __half2 h2 = __floats2half2_rn(v1.x, v1.y);
    __half2 h3 = __floats2half2_rn(v1.z, v1.w);
    ntu4 o;
    o.x = *(const unsigned int*)&h0;
    o.y = *(const unsigned int*)&h1;
    o.z = *(const unsigned int*)&h2;
    o.w = *(const unsigned int*)&h3;
    __builtin_nontemporal_store(o, (ntu4*)out + i);
}

__device__ __forceinline__ float2 h2f(unsigned short lo, unsigned short hi)
{
    __half2 h = __halves2half2(__ushort_as_half(lo), __ushort_as_half(hi));
    return __half22float2(h);
}

__device__ __forceinline__ void acc_h(float4& acc, const ushort4& b)
{
    float2 f01 = h2f(b.x, b.y);
    float2 f23 = h2f(b.z, b.w);
    acc.x += f01.x; acc.y += f01.y; acc.z += f23.x; acc.w += f23.y;
}

// ============ fused bucket-sort + reduce (one block per bucket) ==========

__global__ __launch_bounds__(CTH) void sp_reduce_f(
    const ushort4* __restrict__ feat16,    // [N_NODES][32] ushort4
    const int* __restrict__ pairs,
    const int* __restrict__ cursor_g,
    const int* __restrict__ ovf_cnt,
    const int2* __restrict__ ovf,
    float4* __restrict__ out4)             // [N_SEG][32] float4
{
    __shared__ int cnt[SEGS_PER_B];
    __shared__ int beg[SEGS_PER_B];
    __shared__ int cur[SEGS_PER_B];
    __shared__ int sh[SEGS_PER_B];
    __shared__ int snid[CAP_B];            // 16KB, segment-sorted nids
    int B = blockIdx.x, tid = threadIdx.x;
    int total = cursor_g[B];
    int mc = min(total, CAP_B);
    const int* bp = pairs + B * CAP_B;

    if (tid < SEGS_PER_B) cnt[tid] = 0;
    __syncthreads();
    for (int i = tid; i < mc; i += CTH)
        atomicAdd(&cnt[(bp[i] >> NID_BITS) & (SEGS_PER_B - 1)], 1);
    __syncthreads();

    int c = (tid < SEGS_PER_B) ? cnt[tid] : 0;
    if (tid < SEGS_PER_B) sh[tid] = c;
    __syncthreads();
    for (int o = 1; o < SEGS_PER_B; o <<= 1) {
        int t = (tid < SEGS_PER_B && tid >= o) ? sh[tid - o] : 0;
        __syncthreads();
        if (tid < SEGS_PER_B) sh[tid] += t;
        __syncthreads();
    }
    if (tid < SEGS_PER_B) { beg[tid] = sh[tid] - c; cur[tid] = sh[tid] - c; }
    __syncthreads();

    for (int i = tid; i < mc; i += CTH) {
        int p  = bp[i];
        int sl = (p >> NID_BITS) & (SEGS_PER_B - 1);
        int r  = atomicAdd(&cur[sl], 1);
        snid[r] = p & NID_MASK;
    }
    __syncthreads();

    int ovfB = total - mc;                 // >0 -> this bucket overflowed
    int ovn  = (ovfB > 0) ? min(*ovf_cnt, OVF_CAP) : 0;

    int hw = tid >> 5, lane = tid & 31;    // 16 half-waves x 16 segments
    for (int t = 0; t < SEGS_PER_B / 16; ++t) {
        int sl = hw * (SEGS_PER_B / 16) + t;
        int s  = (B << BSHIFT) + sl;
        if (s >= N_SEG) continue;
        int nst = cnt[sl], bg = beg[sl];
        int m2  = (nst < 32) ? nst : 32;
        int myid = (lane < m2) ? snid[bg + lane] : 0;

        float4 acc0 = make_float4(0.f, 0.f, 0.f, 0.f);
        float4 acc1 = make_float4(0.f, 0.f, 0.f, 0.f);
        if (m2 > 0) {
            int last = m2 - 1;
            for (int j0 = 0; j0 < m2; j0 += 8) {
                int id[8];
#pragma unroll
                for (int k = 0; k < 8; ++k) {
                    int jj = j0 + k;
                    id[k] = __shfl(myid, (jj < last) ? jj : last, 32);
                }
                ushort4 b[8];
#pragma unroll
                for (int k = 0; k < 8; ++k)
                    b[k] = feat16[(size_t)id[k] * 32 + lane];
#pragma unroll
                for (int k = 0; k < 8; ++k) {
                    if (j0 + k < m2) {
                        if (k & 1) acc_h(acc1, b[k]);
                        else       acc_h(acc0, b[k]);
                    }
                }
            }
            for (int k = 32; k < nst; ++k)          // n>32: LDS-resident tail
                acc_h(acc0, feat16[(size_t)snid[bg + k] * 32 + lane]);
        }
        int ntrue = nst;
        if (ovfB > 0) {                             // exact overflow drain
            for (int k = 0; k < ovn; ++k) {
                int2 e = ovf[k];
                if (e.x == s) {
                    acc_h(acc0, feat16[(size_t)e.y * 32 + lane]);
                    ++ntrue;
                }
            }
        }
        float inv = 1.0f / (float)((ntrue > 0) ? ntrue : 1);
        nt4 r;
        r.x = (acc0.x + acc1.x) * inv;
        r.y = (acc0.y + acc1.y) * inv;
        r.z = (acc0.z + acc1.z) * inv;
        r.w = (acc0.w + acc1.w) * inv;
        __builtin_nontemporal_store(
            r, reinterpret_cast<nt4*>(out4) + (size_t)s * 32 + lane);
    }
}

// ================= fallback path (verified fp32 rank path) ===============

__global__ __launch_bounds__(256) void sp_hist_rank(
    const int* __restrict__ sid, int* __restrict__ cnt,
    int* __restrict__ rank, int n)
{
    int i = blockIdx.x * blockDim.x + threadIdx.x;
    if (i >= n) return;
    int s = sid[i];
    rank[i] = atomicAdd(&cnt[s], 1);
}

__global__ __launch_bounds__(256) void sp_scan_local(
    const int* __restrict__ cnt, int* __restrict__ off, int* __restrict__ bsum)
{
    __shared__ int sh[256];
    int tid  = threadIdx.x;
    int base = blockIdx.x * SCAN_CHUNK + tid * 4;
    int v0 = (base + 0 < N_SEG) ? cnt[base + 0] : 0;
    int v1 = (base + 1 < N_SEG) ? cnt[base + 1] : 0;
    int v2 = (base + 2 < N_SEG) ? cnt[base + 2] : 0;
    int v3 = (base + 3 < N_SEG) ? cnt[base + 3] : 0;
    sh[tid] = v0 + v1 + v2 + v3;
    __syncthreads();
    for (int o = 1; o < 256; o <<= 1) {
        int t = (tid >= o) ? sh[tid - o] : 0;
        __syncthreads();
        sh[tid] += t;
        __syncthreads();
    }
    int excl = (tid > 0) ? sh[tid - 1] : 0;
    if (base + 0 < N_SEG) off[base + 0] = excl;
    if (base + 1 < N_SEG) off[base + 1] = excl + v0;
    if (base + 2 < N_SEG) off[base + 2] = excl + v0 + v1;
    if (base + 3 < N_SEG) off[base + 3] = excl + v0 + v1 + v2;
    if (tid == 255) bsum[blockIdx.x] = sh[255];
}

__global__ __launch_bounds__(256) void sp_scan_blocks(int* __restrict__ bsum)
{
    __shared__ int sh[256];
    int tid = threadIdx.x;
    int v = (tid < SCAN_BLOCKS) ? bsum[tid] : 0;
    sh[tid] = v;
    __syncthreads();
    for (int o = 1; o < 256; o <<= 1) {
        int t = (tid >= o) ? sh[tid - o] : 0;
        __syncthreads();
        sh[tid] += t;
        __syncthreads();
    }
    if (tid < SCAN_BLOCKS) bsum[tid] = sh[tid] - v;
}

__global__ __launch_bounds__(256) void sp_reorder_rank(
    const int* __restrict__ nid, const int* __restrict__ sid,
    const int* __restrict__ off, const int* __restrict__ bsum,
    const int* __restrict__ rank, int* __restrict__ sorted_nid, int n)
{
    int i = blockIdx.x * blockDim.x + threadIdx.x;
    if (i >= n) return;
    int s = sid[i];
    sorted_nid[off[s] + bsum[s >> 10] + rank[i]] = nid[i];
}

__global__ __launch_bounds__(256) void sp_reduce(
    const float4* __restrict__ feat4,
    const int* __restrict__ sorted_nid,
    const int* __restrict__ off,
    const int* __restrict__ bsum,
    const int* __restrict__ cnt,
    float4* __restrict__ out4)
{
    int seg  = blockIdx.x * 8 + (threadIdx.x >> 5);
    int lane = threadIdx.x & 31;
    if (seg >= N_SEG) return;

    int n   = cnt[seg];
    int beg = off[seg] + bsum[seg >> 10];
    int m   = (n < 32) ? n : 32;
    int myid = (lane < m) ? sorted_nid[beg + lane] : 0;

    float4 acc0 = make_float4(0.f, 0.f, 0.f, 0.f);
    float4 acc1 = make_float4(0.f, 0.f, 0.f, 0.f);

    if (m > 0) {
        int last = m - 1;
        for (int j0 = 0; j0 < m; j0 += 8) {
            int id[8];
#pragma unroll
            for (int k = 0; k < 8; ++k) {
                int jj = j0 + k;
                id[k] = __shfl(myid, (jj < last) ? jj : last, 32);
            }
            float4 b[8];
#pragma unroll
            for (int k = 0; k < 8; ++k)
                b[k] = feat4[(size_t)id[k] * 32 + lane];
#pragma unroll
            for (int k = 0; k < 8; ++k) {
                if (j0 + k < m) {
                    if (k & 1) {
                        acc1.x += b[k].x; acc1.y += b[k].y;
                        acc1.z += b[k].z; acc1.w += b[k].w;
                    } else {
                        acc0.x += b[k].x; acc0.y += b[k].y;
                        acc0.z += b[k].z; acc0.w += b[k].w;
                    }
                }
            }
        }
        for (int k = 32; k < n; ++k) {
            int nk = sorted_nid[beg + k];
            float4 a = feat4[(size_t)nk * 32 + lane];
            acc0.x += a.x; acc0.y += a.y; acc0.z += a.z; acc0.w += a.w;
        }
    }

    float inv = 1.0f / (float)((n > 0) ? n : 1);
    nt4 r;
    r.x = (acc0.x + acc1.x) * inv;
    r.y = (acc0.y + acc1.y) * inv;
    r.z = (acc0.z + acc1.z) * inv;
    r.w = (acc0.w + acc1.w) * inv;
    __builtin_nontemporal_store(
        r, reinterpret_cast<nt4*>(out4) + (size_t)seg * 32 + lane);
}

// ================= launch =================

extern "C" void kernel_launch(void* const* d_in, const int* in_sizes, int n_in,
                              void* d_out, int out_size, void* d_ws, size_t ws_size,
                              hipStream_t stream) {
    const float* feat = (const float*)d_in[0];
    const int*   nid  = (const int*)d_in[1];
    const int*   sid  = (const int*)d_in[2];
    const int n_edges = in_sizes[1];

    if (ws_size >= WS_NEED_H && n_edges > 0) {
        int* cursor  = NP_CUR(d_ws);
        int* ovfc    = NP_OVFC(d_ws);
        int2* ovf    = NP_OVF(d_ws);
        int* pairs   = NP_PAIRS(d_ws);
        unsigned int* feat16 = (unsigned int*)NP_F16(d_ws);

        hipMemsetAsync(d_ws, 0, 8192, stream);          // cursors + ovf_cnt
        int n8 = N_NODES * D_FEAT / 8;
        sp_cvt<<<(n8 + 255) / 256, 256, 0, stream>>>(feat, feat16, n8);
        int sb = (n_edges + EPB - 1) / EPB;
        sp_bucket_scatter<<<sb, CTH, 0, stream>>>(sid, nid, cursor, pairs,
                                                  ovfc, ovf, n_edges);
        sp_reduce_f<<<NB, CTH, 0, stream>>>((const ushort4*)feat16, pairs,
                                            cursor, ovfc, ovf,
                                            (float4*)d_out);
    } else {
        // fallback: verified fp32 rank path
        int* cnt    = RP_CNT(d_ws);
        int* off    = RP_OFF(d_ws);
        int* bsum   = RP_BSUM(d_ws);
        int* rank   = RP_RANK(d_ws);
        int* sorted = RP_SORTED(d_ws);
        int eb = (n_edges + 255) / 256;
        int rb = (N_SEG + 7) / 8;

        hipMemsetAsync(d_ws, 0, (size_t)(1u << 20), stream);
        sp_hist_rank<<<eb, 256, 0, stream>>>(sid, cnt, rank, n_edges);
        sp_scan_local<<<SCAN_BLOCKS, 256, 0, stream>>>(cnt, off, bsum);
        sp_scan_blocks<<<1, 256, 0, stream>>>(bsum);
        sp_reorder_rank<<<eb, 256, 0, stream>>>(nid, sid, off, bsum, rank,
                                                sorted, n_edges);
        sp_reduce<<<rb, 256, 0, stream>>>((const float4*)feat, sorted, off,
                                          bsum, cnt, (float4*)d_out);
    }
}